// Round 1
// baseline (263.865 us; speedup 1.0000x reference)
//
#include <hip/hip_runtime.h>
#include <hip/hip_bf16.h>

typedef __attribute__((ext_vector_type(8))) short short8;   // 8 bf16 = 16B
typedef __attribute__((ext_vector_type(4))) float f32x4;

#define GAS(p) ((const __attribute__((address_space(1))) void*)(p))
#define LAS(p) ((__attribute__((address_space(3))) void*)(p))

__device__ __forceinline__ short f2bf_bits(float f) {
    __hip_bfloat16 h = __float2bfloat16(f);
    return *reinterpret_cast<short*>(&h);
}

// ---------------- fp32 -> bf16 conversion (vectorized, G13) ----------------
__global__ __launch_bounds__(256) void cvt_bf16(const float* __restrict__ src,
                                                short* __restrict__ dst, int n) {
    int i = (blockIdx.x * 256 + threadIdx.x) * 8;
    if (i >= n) return;
    float4 a = *reinterpret_cast<const float4*>(src + i);
    float4 b = *reinterpret_cast<const float4*>(src + i + 4);
    short8 o;
    o[0] = f2bf_bits(a.x); o[1] = f2bf_bits(a.y);
    o[2] = f2bf_bits(a.z); o[3] = f2bf_bits(a.w);
    o[4] = f2bf_bits(b.x); o[5] = f2bf_bits(b.y);
    o[6] = f2bf_bits(b.z); o[7] = f2bf_bits(b.w);
    *reinterpret_cast<short8*>(dst + i) = o;
}

// ---------------- QKV projection GEMM ----------------
// A = xbf [4096][1024], B = wbf [3072][1024] (B^T layout), C[m][e]+bias,
// scatter to Q/K/V [bh][l][64] bf16. Q scaled by 0.125 (exact pow2).
__global__ __launch_bounds__(256) void gemm_qkv(const __hip_bfloat16* __restrict__ A,
                                                const __hip_bfloat16* __restrict__ B,
                                                const float* __restrict__ bias,
                                                __hip_bfloat16* __restrict__ Qb,
                                                __hip_bfloat16* __restrict__ Kb,
                                                __hip_bfloat16* __restrict__ Vb) {
    constexpr int K = 1024;
    __shared__ __hip_bfloat16 smem[2][128 * 32 + 128 * 32];   // A|B tiles, 32KB total
    const int tid = threadIdx.x;
    const int lane = tid & 63, wid = tid >> 6;
    const int wr = wid >> 1, wc = wid & 1;
    const int lr = lane & 15, lg = lane >> 4;
    const int m0 = blockIdx.y * 128;
    const int n0 = blockIdx.x * 128;

    const f32x4 fz = {0.f, 0.f, 0.f, 0.f};
    f32x4 acc[4][4];
#pragma unroll
    for (int i = 0; i < 4; i++)
#pragma unroll
        for (int j = 0; j < 4; j++) acc[i][j] = fz;

    const char* Abase = (const char*)A + (size_t)m0 * K * 2;
    const char* Bbase = (const char*)B + (size_t)n0 * K * 2;

    auto stage = [&](int buf, int kt) {
        const int kb = kt * 64;   // byte offset along K (32 elems)
        char* sA = (char*)&smem[buf][0];
        char* sB = (char*)&smem[buf][128 * 32];
#pragma unroll
        for (int i = 0; i < 2; i++) {
            int o = i * 4096 + tid * 16;
            int row = o >> 6, cb = o & 63;   // 64B per LDS row (BK=32 bf16)
            __builtin_amdgcn_global_load_lds(GAS(Abase + (size_t)row * 2048 + kb + cb),
                                             LAS(sA + o), 16, 0, 0);
        }
#pragma unroll
        for (int i = 0; i < 2; i++) {
            int o = i * 4096 + tid * 16;
            int row = o >> 6, cb = o & 63;
            __builtin_amdgcn_global_load_lds(GAS(Bbase + (size_t)row * 2048 + kb + cb),
                                             LAS(sB + o), 16, 0, 0);
        }
    };

    stage(0, 0);
    __syncthreads();
    int buf = 0;
    constexpr int NT = K / 32;
    for (int kt = 0; kt < NT; ++kt) {
        if (kt + 1 < NT) stage(buf ^ 1, kt + 1);
        const __hip_bfloat16* sA = &smem[buf][0];
        const __hip_bfloat16* sB = &smem[buf][128 * 32];
        short8 a[4], b[4];
#pragma unroll
        for (int i = 0; i < 4; i++)
            a[i] = *reinterpret_cast<const short8*>(sA + (wr * 64 + i * 16 + lr) * 32 + lg * 8);
#pragma unroll
        for (int j = 0; j < 4; j++)
            b[j] = *reinterpret_cast<const short8*>(sB + (wc * 64 + j * 16 + lr) * 32 + lg * 8);
#pragma unroll
        for (int i = 0; i < 4; i++)
#pragma unroll
            for (int j = 0; j < 4; j++)
                acc[i][j] = __builtin_amdgcn_mfma_f32_16x16x32_bf16(a[i], b[j], acc[i][j], 0, 0, 0);
        __syncthreads();   // drains vmcnt -> next tile staged; protects buf reuse
        buf ^= 1;
    }

    // epilogue: C[m][e] = acc + bias[e]; scatter into Q/K/V
#pragma unroll
    for (int j = 0; j < 4; j++) {
        int e = n0 + wc * 64 + j * 16 + lr;
        float bv = bias[e];
        int sec = e >> 10;           // 0=Q 1=K 2=V (uniform per block)
        int el = e & 1023;
        int h = el >> 6, d = el & 63;
        __hip_bfloat16* dst = (sec == 0) ? Qb : ((sec == 1) ? Kb : Vb);
        float scale = (sec == 0) ? 0.125f : 1.0f;
#pragma unroll
        for (int i = 0; i < 4; i++) {
            int mb = m0 + wr * 64 + i * 16 + lg * 4;
#pragma unroll
            for (int r = 0; r < 4; r++) {
                int tok = mb + r;
                int bb = tok >> 11, l = tok & 2047;
                float v = (acc[i][j][r] + bv) * scale;
                dst[((size_t)(bb * 16 + h) * 2048 + l) * 64 + d] = __float2bfloat16(v);
            }
        }
    }
}

// ---------------- V transpose: [bh][l][64] -> [bh][64][L] ----------------
__global__ __launch_bounds__(256) void transpose_v(const __hip_bfloat16* __restrict__ V,
                                                   __hip_bfloat16* __restrict__ Vt) {
    __shared__ unsigned short tb[64][72];   // padded
    int bh = blockIdx.y, l0 = blockIdx.x * 64;
    int tid = threadIdx.x;
    const unsigned short* src = (const unsigned short*)V + ((size_t)bh * 2048 + l0) * 64;
#pragma unroll
    for (int i = 0; i < 2; i++) {
        int idx = i * 256 + tid;
        int row = idx >> 3;             // l offset
        int c0 = (idx & 7) * 8;         // d offset
        short8 v = *reinterpret_cast<const short8*>(src + row * 64 + c0);
#pragma unroll
        for (int jj = 0; jj < 8; jj++) tb[c0 + jj][row] = (unsigned short)v[jj];
    }
    __syncthreads();
    unsigned short* dst = (unsigned short*)Vt + (size_t)bh * 64 * 2048 + l0;
#pragma unroll
    for (int i = 0; i < 2; i++) {
        int idx = i * 256 + tid;
        int d = idx >> 3;
        int c8 = (idx & 7) * 8;         // l offset
        short8 vv = *reinterpret_cast<const short8*>(&tb[d][c8]);
        *reinterpret_cast<short8*>(dst + (size_t)d * 2048 + c8) = vv;
    }
}

// ---------------- causal flash attention ----------------
// grid: (32 q-tiles descending, 32 bh); 4 waves, each owns 16 q-rows.
// K_lds/Vt_lds XOR-swizzled via pre-swizzled global_load_lds source (rule 21).
__global__ __launch_bounds__(256) void attn(const __hip_bfloat16* __restrict__ Qg,
                                            const __hip_bfloat16* __restrict__ Kg,
                                            const __hip_bfloat16* __restrict__ Vtg,
                                            __hip_bfloat16* __restrict__ ctx) {
    const int bh = blockIdx.y;
    const int qt = gridDim.x - 1 - blockIdx.x;   // biggest blocks first
    const int q0 = qt * 64;
    const int tid = threadIdx.x, lane = tid & 63, wq = tid >> 6;
    const int lr = lane & 15, lg = lane >> 4;
    const int qb = q0 + wq * 16;

    __shared__ __hip_bfloat16 Ks[2][64 * 64];    // [kv][dh], swizzled slots
    __shared__ __hip_bfloat16 Vs[2][64 * 64];    // [d][kv],  swizzled slots
    __shared__ __hip_bfloat16 Ps[4][16 * 72];    // per-wave P [q][kv], padded

    // Q fragments in registers (A-operand rows = lane&15)
    const __hip_bfloat16* Qrow = Qg + ((size_t)bh * 2048 + qb + lr) * 64 + lg * 8;
    short8 qf0 = *reinterpret_cast<const short8*>(Qrow);
    short8 qf1 = *reinterpret_cast<const short8*>(Qrow + 32);

    const f32x4 fz = {0.f, 0.f, 0.f, 0.f};
    f32x4 o[4];
#pragma unroll
    for (int n = 0; n < 4; n++) o[n] = fz;
    float mrow[4] = {-1e30f, -1e30f, -1e30f, -1e30f};
    float lrow[4] = {0.f, 0.f, 0.f, 0.f};

    const char* kbase = (const char*)Kg + (size_t)bh * 2048 * 64 * 2;
    const char* vbase = (const char*)Vtg + (size_t)bh * 64 * 2048 * 2;

    auto stage = [&](int buf, int kt) {
        int kv0 = kt * 64;
        char* sK = (char*)&Ks[buf][0];
        char* sV = (char*)&Vs[buf][0];
#pragma unroll
        for (int i = 0; i < 2; i++) {
            int o_ = i * 4096 + tid * 16;
            int row = o_ >> 7;              // 128B LDS rows
            int slot = (o_ >> 4) & 7;
            int sl = slot ^ (row & 7);      // inverse-swizzled source slot
            __builtin_amdgcn_global_load_lds(
                GAS(kbase + ((size_t)(kv0 + row) * 64) * 2 + sl * 16), LAS(sK + o_), 16, 0, 0);
        }
#pragma unroll
        for (int i = 0; i < 2; i++) {
            int o_ = i * 4096 + tid * 16;
            int row = o_ >> 7;              // d
            int slot = (o_ >> 4) & 7;
            int sl = slot ^ (row & 7);
            __builtin_amdgcn_global_load_lds(
                GAS(vbase + ((size_t)row * 2048 + kv0) * 2 + sl * 16), LAS(sV + o_), 16, 0, 0);
        }
    };

    const int NT = qt + 1;
    stage(0, 0);
    __syncthreads();
    int buf = 0;
    for (int kt = 0; kt < NT; ++kt) {
        if (kt + 1 < NT) stage(buf ^ 1, kt + 1);
        const __hip_bfloat16* sK = &Ks[buf][0];
        const __hip_bfloat16* sV = &Vs[buf][0];

        // S = Q K^T  (16 q-rows x 64 kv per wave)
        f32x4 s[4];
#pragma unroll
        for (int n = 0; n < 4; n++) s[n] = fz;
#pragma unroll
        for (int n = 0; n < 4; n++) {
            int kv = n * 16 + lr;
            short8 k0 = *reinterpret_cast<const short8*>(sK + kv * 64 + ((lg ^ (kv & 7)) * 8));
            short8 k1 = *reinterpret_cast<const short8*>(sK + kv * 64 + (((4 + lg) ^ (kv & 7)) * 8));
            s[n] = __builtin_amdgcn_mfma_f32_16x16x32_bf16(qf0, k0, s[n], 0, 0, 0);
            s[n] = __builtin_amdgcn_mfma_f32_16x16x32_bf16(qf1, k1, s[n], 0, 0, 0);
        }
        // causal mask on the diagonal tile (uniform branch)
        if (kt == NT - 1) {
#pragma unroll
            for (int n = 0; n < 4; n++) {
                int kv = kt * 64 + n * 16 + lr;
#pragma unroll
                for (int r = 0; r < 4; r++) {
                    int q = qb + lg * 4 + r;
                    if (kv > q) s[n][r] = -1e30f;
                }
            }
        }
        // online softmax (wave-parallel, 16-lane butterflies)
#pragma unroll
        for (int r = 0; r < 4; r++) {
            float mx = fmaxf(fmaxf(s[0][r], s[1][r]), fmaxf(s[2][r], s[3][r]));
            mx = fmaxf(mx, __shfl_xor(mx, 1));
            mx = fmaxf(mx, __shfl_xor(mx, 2));
            mx = fmaxf(mx, __shfl_xor(mx, 4));
            mx = fmaxf(mx, __shfl_xor(mx, 8));
            float mnew = fmaxf(mrow[r], mx);
            float corr = __expf(mrow[r] - mnew);
            mrow[r] = mnew;
            float ps = 0.f;
#pragma unroll
            for (int n = 0; n < 4; n++) {
                float p = __expf(s[n][r] - mnew);
                s[n][r] = p;
                ps += p;
            }
            ps += __shfl_xor(ps, 1);
            ps += __shfl_xor(ps, 2);
            ps += __shfl_xor(ps, 4);
            ps += __shfl_xor(ps, 8);
            lrow[r] = lrow[r] * corr + ps;
#pragma unroll
            for (int n = 0; n < 4; n++) o[n][r] *= corr;
        }
        // P -> LDS (bf16), per-wave region, then PV
        __hip_bfloat16* pw = &Ps[wq][0];
#pragma unroll
        for (int n = 0; n < 4; n++)
#pragma unroll
            for (int r = 0; r < 4; r++)
                pw[(lg * 4 + r) * 72 + n * 16 + lr] = __float2bfloat16(s[n][r]);
        asm volatile("s_waitcnt lgkmcnt(0)" ::: "memory");
#pragma unroll
        for (int ks = 0; ks < 2; ks++) {
            short8 pa = *reinterpret_cast<const short8*>(pw + lr * 72 + ks * 32 + lg * 8);
#pragma unroll
            for (int n = 0; n < 4; n++) {
                int d = n * 16 + lr;
                short8 vf = *reinterpret_cast<const short8*>(sV + d * 64 + (((ks * 4 + lg) ^ (d & 7)) * 8));
                o[n] = __builtin_amdgcn_mfma_f32_16x16x32_bf16(pa, vf, o[n], 0, 0, 0);
            }
        }
        __syncthreads();
        buf ^= 1;
    }

    // normalize + store ctx bf16 [tok][h*64+d]
    int bb = bh >> 4, h = bh & 15;
#pragma unroll
    for (int r = 0; r < 4; r++) {
        float inv = 1.0f / lrow[r];
        int tok = qb + lg * 4 + r;
        __hip_bfloat16* crow = ctx + ((size_t)(bb * 2048 + tok)) * 1024 + h * 64;
#pragma unroll
        for (int n = 0; n < 4; n++) crow[n * 16 + lr] = __float2bfloat16(o[n][r] * inv);
    }
}

// ---------------- output projection GEMM (128x64 tile) ----------------
__global__ __launch_bounds__(256) void gemm_out(const __hip_bfloat16* __restrict__ A,
                                                const __hip_bfloat16* __restrict__ B,
                                                const float* __restrict__ bias,
                                                float* __restrict__ out) {
    constexpr int K = 1024;
    __shared__ __hip_bfloat16 smem[2][128 * 32 + 64 * 32];
    const int tid = threadIdx.x;
    const int lane = tid & 63, wid = tid >> 6;
    const int wr = wid >> 1, wc = wid & 1;
    const int lr = lane & 15, lg = lane >> 4;
    const int m0 = blockIdx.y * 128;
    const int n0 = blockIdx.x * 64;

    const f32x4 fz = {0.f, 0.f, 0.f, 0.f};
    f32x4 acc[4][2];
#pragma unroll
    for (int i = 0; i < 4; i++)
#pragma unroll
        for (int j = 0; j < 2; j++) acc[i][j] = fz;

    const char* Abase = (const char*)A + (size_t)m0 * K * 2;
    const char* Bbase = (const char*)B + (size_t)n0 * K * 2;

    auto stage = [&](int buf, int kt) {
        const int kb = kt * 64;
        char* sA = (char*)&smem[buf][0];
        char* sB = (char*)&smem[buf][128 * 32];
#pragma unroll
        for (int i = 0; i < 2; i++) {
            int o = i * 4096 + tid * 16;
            int row = o >> 6, cb = o & 63;
            __builtin_amdgcn_global_load_lds(GAS(Abase + (size_t)row * 2048 + kb + cb),
                                             LAS(sA + o), 16, 0, 0);
        }
        {
            int o = tid * 16;
            int row = o >> 6, cb = o & 63;
            __builtin_amdgcn_global_load_lds(GAS(Bbase + (size_t)row * 2048 + kb + cb),
                                             LAS(sB + o), 16, 0, 0);
        }
    };

    stage(0, 0);
    __syncthreads();
    int buf = 0;
    constexpr int NT = K / 32;
    for (int kt = 0; kt < NT; ++kt) {
        if (kt + 1 < NT) stage(buf ^ 1, kt + 1);
        const __hip_bfloat16* sA = &smem[buf][0];
        const __hip_bfloat16* sB = &smem[buf][128 * 32];
        short8 a[4], b[2];
#pragma unroll
        for (int i = 0; i < 4; i++)
            a[i] = *reinterpret_cast<const short8*>(sA + (wr * 64 + i * 16 + lr) * 32 + lg * 8);
#pragma unroll
        for (int j = 0; j < 2; j++)
            b[j] = *reinterpret_cast<const short8*>(sB + (wc * 32 + j * 16 + lr) * 32 + lg * 8);
#pragma unroll
        for (int i = 0; i < 4; i++)
#pragma unroll
            for (int j = 0; j < 2; j++)
                acc[i][j] = __builtin_amdgcn_mfma_f32_16x16x32_bf16(a[i], b[j], acc[i][j], 0, 0, 0);
        __syncthreads();
        buf ^= 1;
    }

#pragma unroll
    for (int j = 0; j < 2; j++) {
        int e = n0 + wc * 32 + j * 16 + lr;
        float bv = bias[e];
#pragma unroll
        for (int i = 0; i < 4; i++) {
            int mb = m0 + wr * 64 + i * 16 + lg * 4;
#pragma unroll
            for (int r = 0; r < 4; r++) {
                out[(size_t)(mb + r) * 1024 + e] = acc[i][j][r] + bv;
            }
        }
    }
}

extern "C" void kernel_launch(void* const* d_in, const int* in_sizes, int n_in,
                              void* d_out, int out_size, void* d_ws, size_t ws_size,
                              hipStream_t stream) {
    const float* x = (const float*)d_in[0];
    const float* w_in = (const float*)d_in[1];
    const float* b_in = (const float*)d_in[2];
    const float* w_out = (const float*)d_in[3];
    const float* b_out = (const float*)d_in[4];
    float* out = (float*)d_out;

    char* ws = (char*)d_ws;
    __hip_bfloat16* xbf  = (__hip_bfloat16*)(ws);                       // 8 MB
    __hip_bfloat16* wbf  = (__hip_bfloat16*)(ws + (8ull << 20));        // 6 MB
    __hip_bfloat16* owbf = (__hip_bfloat16*)(ws + (14ull << 20));       // 2 MB
    __hip_bfloat16* Qb   = (__hip_bfloat16*)(ws + (16ull << 20));       // 8 MB
    __hip_bfloat16* Kb   = (__hip_bfloat16*)(ws + (24ull << 20));       // 8 MB
    __hip_bfloat16* Vb   = (__hip_bfloat16*)(ws + (32ull << 20));       // 8 MB
    __hip_bfloat16* Vt   = (__hip_bfloat16*)(ws + (40ull << 20));       // 8 MB
    __hip_bfloat16* ctxb = (__hip_bfloat16*)(ws + (48ull << 20));       // 8 MB

    cvt_bf16<<<2048, 256, 0, stream>>>(x, (short*)xbf, 4194304);
    cvt_bf16<<<1536, 256, 0, stream>>>(w_in, (short*)wbf, 3145728);
    cvt_bf16<<<512, 256, 0, stream>>>(w_out, (short*)owbf, 1048576);
    gemm_qkv<<<dim3(24, 32), 256, 0, stream>>>(xbf, wbf, b_in, Qb, Kb, Vb);
    transpose_v<<<dim3(32, 32), 256, 0, stream>>>(Vb, Vt);
    attn<<<dim3(32, 32), 256, 0, stream>>>(Qb, Kb, Vt, ctxb);
    gemm_out<<<dim3(16, 32), 256, 0, stream>>>(ctxb, owbf, b_out, out);
}

// Round 2
// 199.465 us; speedup vs baseline: 1.3229x; 1.3229x over previous
//
#include <hip/hip_runtime.h>
#include <hip/hip_bf16.h>

typedef __attribute__((ext_vector_type(8))) short short8;   // 8 bf16 = 16B
typedef __attribute__((ext_vector_type(4))) short short4v;  // 4 bf16 = 8B
typedef __attribute__((ext_vector_type(4))) float f32x4;

#define GAS(p) ((const __attribute__((address_space(1))) void*)(p))
#define LAS(p) ((__attribute__((address_space(3))) void*)(p))

__device__ __forceinline__ short f2bf_bits(float f) {
    __hip_bfloat16 h = __float2bfloat16(f);
    return *reinterpret_cast<short*>(&h);
}

// ---------------- fp32 -> bf16 conversion (vectorized, G13) ----------------
__global__ __launch_bounds__(256) void cvt_bf16(const float* __restrict__ src,
                                                short* __restrict__ dst, int n) {
    int i = (blockIdx.x * 256 + threadIdx.x) * 8;
    if (i >= n) return;
    float4 a = *reinterpret_cast<const float4*>(src + i);
    float4 b = *reinterpret_cast<const float4*>(src + i + 4);
    short8 o;
    o[0] = f2bf_bits(a.x); o[1] = f2bf_bits(a.y);
    o[2] = f2bf_bits(a.z); o[3] = f2bf_bits(a.w);
    o[4] = f2bf_bits(b.x); o[5] = f2bf_bits(b.y);
    o[6] = f2bf_bits(b.z); o[7] = f2bf_bits(b.w);
    *reinterpret_cast<short8*>(dst + i) = o;
}

// ---------------- QKV projection GEMM ----------------
__global__ __launch_bounds__(256) void gemm_qkv(const __hip_bfloat16* __restrict__ A,
                                                const __hip_bfloat16* __restrict__ B,
                                                const float* __restrict__ bias,
                                                __hip_bfloat16* __restrict__ Qb,
                                                __hip_bfloat16* __restrict__ Kb,
                                                __hip_bfloat16* __restrict__ Vb) {
    constexpr int K = 1024;
    __shared__ __hip_bfloat16 smem[2][128 * 32 + 128 * 32];
    const int tid = threadIdx.x;
    const int lane = tid & 63, wid = tid >> 6;
    const int wr = wid >> 1, wc = wid & 1;
    const int lr = lane & 15, lg = lane >> 4;
    const int m0 = blockIdx.y * 128;
    const int n0 = blockIdx.x * 128;

    const f32x4 fz = {0.f, 0.f, 0.f, 0.f};
    f32x4 acc[4][4];
#pragma unroll
    for (int i = 0; i < 4; i++)
#pragma unroll
        for (int j = 0; j < 4; j++) acc[i][j] = fz;

    const char* Abase = (const char*)A + (size_t)m0 * K * 2;
    const char* Bbase = (const char*)B + (size_t)n0 * K * 2;

    auto stage = [&](int buf, int kt) {
        const int kb = kt * 64;
        char* sA = (char*)&smem[buf][0];
        char* sB = (char*)&smem[buf][128 * 32];
#pragma unroll
        for (int i = 0; i < 2; i++) {
            int o = i * 4096 + tid * 16;
            int row = o >> 6, cb = o & 63;
            __builtin_amdgcn_global_load_lds(GAS(Abase + (size_t)row * 2048 + kb + cb),
                                             LAS(sA + o), 16, 0, 0);
        }
#pragma unroll
        for (int i = 0; i < 2; i++) {
            int o = i * 4096 + tid * 16;
            int row = o >> 6, cb = o & 63;
            __builtin_amdgcn_global_load_lds(GAS(Bbase + (size_t)row * 2048 + kb + cb),
                                             LAS(sB + o), 16, 0, 0);
        }
    };

    stage(0, 0);
    __syncthreads();
    int buf = 0;
    constexpr int NT = K / 32;
    for (int kt = 0; kt < NT; ++kt) {
        if (kt + 1 < NT) stage(buf ^ 1, kt + 1);
        const __hip_bfloat16* sA = &smem[buf][0];
        const __hip_bfloat16* sB = &smem[buf][128 * 32];
        short8 a[4], b[4];
#pragma unroll
        for (int i = 0; i < 4; i++)
            a[i] = *reinterpret_cast<const short8*>(sA + (wr * 64 + i * 16 + lr) * 32 + lg * 8);
#pragma unroll
        for (int j = 0; j < 4; j++)
            b[j] = *reinterpret_cast<const short8*>(sB + (wc * 64 + j * 16 + lr) * 32 + lg * 8);
#pragma unroll
        for (int i = 0; i < 4; i++)
#pragma unroll
            for (int j = 0; j < 4; j++)
                acc[i][j] = __builtin_amdgcn_mfma_f32_16x16x32_bf16(a[i], b[j], acc[i][j], 0, 0, 0);
        __syncthreads();
        buf ^= 1;
    }

#pragma unroll
    for (int j = 0; j < 4; j++) {
        int e = n0 + wc * 64 + j * 16 + lr;
        float bv = bias[e];
        int sec = e >> 10;
        int el = e & 1023;
        int h = el >> 6, d = el & 63;
        __hip_bfloat16* dst = (sec == 0) ? Qb : ((sec == 1) ? Kb : Vb);
        float scale = (sec == 0) ? 0.125f : 1.0f;
#pragma unroll
        for (int i = 0; i < 4; i++) {
            int mb = m0 + wr * 64 + i * 16 + lg * 4;
#pragma unroll
            for (int r = 0; r < 4; r++) {
                int tok = mb + r;
                int bb = tok >> 11, l = tok & 2047;
                float v = (acc[i][j][r] + bv) * scale;
                dst[((size_t)(bb * 16 + h) * 2048 + l) * 64 + d] = __float2bfloat16(v);
            }
        }
    }
}

// ---------------- V transpose: [bh][l][64] -> [bh][64][L] ----------------
__global__ __launch_bounds__(256) void transpose_v(const __hip_bfloat16* __restrict__ V,
                                                   __hip_bfloat16* __restrict__ Vt) {
    __shared__ unsigned short tb[64][72];
    int bh = blockIdx.y, l0 = blockIdx.x * 64;
    int tid = threadIdx.x;
    const unsigned short* src = (const unsigned short*)V + ((size_t)bh * 2048 + l0) * 64;
#pragma unroll
    for (int i = 0; i < 2; i++) {
        int idx = i * 256 + tid;
        int row = idx >> 3;
        int c0 = (idx & 7) * 8;
        short8 v = *reinterpret_cast<const short8*>(src + row * 64 + c0);
#pragma unroll
        for (int jj = 0; jj < 8; jj++) tb[c0 + jj][row] = (unsigned short)v[jj];
    }
    __syncthreads();
    unsigned short* dst = (unsigned short*)Vt + (size_t)bh * 64 * 2048 + l0;
#pragma unroll
    for (int i = 0; i < 2; i++) {
        int idx = i * 256 + tid;
        int d = idx >> 3;
        int c8 = (idx & 7) * 8;
        short8 vv = *reinterpret_cast<const short8*>(&tb[d][c8]);
        *reinterpret_cast<short8*>(dst + (size_t)d * 2048 + c8) = vv;
    }
}

// ---------------- causal flash attention (swapped QK^T, paired q-tiles) ----
// grid (16, 32): block handles q-tiles {bx, 31-bx} -> 33 KV-iters each, uniform.
// 4 waves x 16 q-rows. Swapped QK^T: S^T = mfma(K, Q) puts a full q-row in
// each lane -> lane-local softmax + 2 shfl_xor. P round-trips via per-wave LDS.
__global__ __launch_bounds__(256) void attn(const __hip_bfloat16* __restrict__ Qg,
                                            const __hip_bfloat16* __restrict__ Kg,
                                            const __hip_bfloat16* __restrict__ Vtg,
                                            __hip_bfloat16* __restrict__ ctx) {
    const int bh = blockIdx.y;
    const int tid = threadIdx.x, lane = tid & 63, wq = tid >> 6;
    const int lr = lane & 15, lg = lane >> 4;

    __shared__ __hip_bfloat16 Ks[2][64 * 64];    // [kv][dh], swizzled 16B slots
    __shared__ __hip_bfloat16 Vs[2][64 * 64];    // [d][kv],  swizzled 16B slots
    __shared__ __hip_bfloat16 Ps[4][16 * 72];    // per-wave P [q][kv], padded

    const char* kbase = (const char*)Kg + (size_t)bh * 2048 * 64 * 2;
    const char* vbase = (const char*)Vtg + (size_t)bh * 64 * 2048 * 2;
    const int bb = bh >> 4, h = bh & 15;

    auto stage = [&](int buf, int kt) {
        int kv0 = kt * 64;
        char* sK = (char*)&Ks[buf][0];
        char* sV = (char*)&Vs[buf][0];
#pragma unroll
        for (int i = 0; i < 2; i++) {
            int o_ = i * 4096 + tid * 16;
            int row = o_ >> 7;
            int slot = (o_ >> 4) & 7;
            int sl = slot ^ (row & 7);
            __builtin_amdgcn_global_load_lds(
                GAS(kbase + ((size_t)(kv0 + row) * 64) * 2 + sl * 16), LAS(sK + o_), 16, 0, 0);
        }
#pragma unroll
        for (int i = 0; i < 2; i++) {
            int o_ = i * 4096 + tid * 16;
            int row = o_ >> 7;
            int slot = (o_ >> 4) & 7;
            int sl = slot ^ (row & 7);
            __builtin_amdgcn_global_load_lds(
                GAS(vbase + ((size_t)row * 2048 + kv0) * 2 + sl * 16), LAS(sV + o_), 16, 0, 0);
        }
    };

    const f32x4 fz = {0.f, 0.f, 0.f, 0.f};

#pragma unroll 1
    for (int seg = 0; seg < 2; ++seg) {
        const int qt = (seg == 0) ? (int)blockIdx.x : 31 - (int)blockIdx.x;
        const int qb = qt * 64 + wq * 16;

        // Q fragments (B-operand): lane holds Q[q=lr][d = lg*8..+8 / 32+lg*8..+8]
        const __hip_bfloat16* Qrow = Qg + ((size_t)bh * 2048 + qb + lr) * 64 + lg * 8;
        short8 qf0 = *reinterpret_cast<const short8*>(Qrow);
        short8 qf1 = *reinterpret_cast<const short8*>(Qrow + 32);

        f32x4 o[4];
#pragma unroll
        for (int n = 0; n < 4; n++) o[n] = fz;
        float m = -1e30f, lsum = 0.f;

        const int NT = qt + 1;
        stage(0, 0);
        __syncthreads();
        int buf = 0;
        for (int kt = 0; kt < NT; ++kt) {
            if (kt + 1 < NT) stage(buf ^ 1, kt + 1);
            const __hip_bfloat16* sK = &Ks[buf][0];
            const __hip_bfloat16* sV = &Vs[buf][0];

            // S^T = K Q^T : D[row=kv_local][col=q]; lane: q=lr, kv=n*16+lg*4+r
            f32x4 s[4];
#pragma unroll
            for (int n = 0; n < 4; n++) s[n] = fz;
#pragma unroll
            for (int n = 0; n < 4; n++) {
                int kv = n * 16 + lr;   // A-operand row index for this lane
                short8 k0 = *reinterpret_cast<const short8*>(sK + kv * 64 + ((lg ^ (kv & 7)) * 8));
                short8 k1 = *reinterpret_cast<const short8*>(sK + kv * 64 + (((4 + lg) ^ (kv & 7)) * 8));
                s[n] = __builtin_amdgcn_mfma_f32_16x16x32_bf16(k0, qf0, s[n], 0, 0, 0);
                s[n] = __builtin_amdgcn_mfma_f32_16x16x32_bf16(k1, qf1, s[n], 0, 0, 0);
            }
            // causal mask on the diagonal tile
            if (kt == NT - 1) {
                int q = qb + lr;
#pragma unroll
                for (int n = 0; n < 4; n++) {
                    int kvb = kt * 64 + n * 16 + lg * 4;
#pragma unroll
                    for (int r = 0; r < 4; r++)
                        if (kvb + r > q) s[n][r] = -1e30f;
                }
            }
            // lane-local online softmax (each lane owns one q-row's 16 values)
            float mx0 = fmaxf(fmaxf(s[0][0], s[0][1]), fmaxf(s[0][2], s[0][3]));
            float mx1 = fmaxf(fmaxf(s[1][0], s[1][1]), fmaxf(s[1][2], s[1][3]));
            float mx2 = fmaxf(fmaxf(s[2][0], s[2][1]), fmaxf(s[2][2], s[2][3]));
            float mx3 = fmaxf(fmaxf(s[3][0], s[3][1]), fmaxf(s[3][2], s[3][3]));
            float mx = fmaxf(fmaxf(mx0, mx1), fmaxf(mx2, mx3));
            mx = fmaxf(mx, __shfl_xor(mx, 16));
            mx = fmaxf(mx, __shfl_xor(mx, 32));
            float mnew = fmaxf(m, mx);
            float corr = __expf(m - mnew);
            m = mnew;
            float ps = 0.f;
#pragma unroll
            for (int n = 0; n < 4; n++) {
#pragma unroll
                for (int r = 0; r < 4; r++) {
                    float p = __expf(s[n][r] - mnew);
                    s[n][r] = p;
                    ps += p;
                }
            }
            ps += __shfl_xor(ps, 16);
            ps += __shfl_xor(ps, 32);
            lsum = lsum * corr + ps;

            // distribute corr to O-layout lanes (q' = lg*4+r lives at lane lr=q')
            float c0 = __shfl(corr, (lane & 48) | ((lg * 4 + 0) & 15));
            float c1 = __shfl(corr, (lane & 48) | ((lg * 4 + 1) & 15));
            float c2 = __shfl(corr, (lane & 48) | ((lg * 4 + 2) & 15));
            float c3 = __shfl(corr, (lane & 48) | ((lg * 4 + 3) & 15));
#pragma unroll
            for (int n = 0; n < 4; n++) {
                o[n][0] *= c0; o[n][1] *= c1; o[n][2] *= c2; o[n][3] *= c3;
            }

            // P -> per-wave LDS (A-fragment layout), 4x ds_write_b64
            __hip_bfloat16* pw = &Ps[wq][0];
#pragma unroll
            for (int n = 0; n < 4; n++) {
                short4v pk;
                pk[0] = f2bf_bits(s[n][0]); pk[1] = f2bf_bits(s[n][1]);
                pk[2] = f2bf_bits(s[n][2]); pk[3] = f2bf_bits(s[n][3]);
                *reinterpret_cast<short4v*>(pw + lr * 72 + n * 16 + lg * 4) = pk;
            }
            asm volatile("s_waitcnt lgkmcnt(0)" ::: "memory");
            short8 pa0 = *reinterpret_cast<const short8*>(pw + lr * 72 + lg * 8);
            short8 pa1 = *reinterpret_cast<const short8*>(pw + lr * 72 + 32 + lg * 8);

            // PV: O[q][d] += P V ; B-operand from Vs[d][kv]
#pragma unroll
            for (int n = 0; n < 4; n++) {
                int d = n * 16 + lr;
                short8 vf0 = *reinterpret_cast<const short8*>(sV + d * 64 + ((lg ^ (d & 7)) * 8));
                short8 vf1 = *reinterpret_cast<const short8*>(sV + d * 64 + (((4 + lg) ^ (d & 7)) * 8));
                o[n] = __builtin_amdgcn_mfma_f32_16x16x32_bf16(pa0, vf0, o[n], 0, 0, 0);
                o[n] = __builtin_amdgcn_mfma_f32_16x16x32_bf16(pa1, vf1, o[n], 0, 0, 0);
            }
            __syncthreads();
            buf ^= 1;
        }

        // epilogue: normalize by lsum (distributed to O layout) and store
        float l0 = __shfl(lsum, (lane & 48) | ((lg * 4 + 0) & 15));
        float l1 = __shfl(lsum, (lane & 48) | ((lg * 4 + 1) & 15));
        float l2 = __shfl(lsum, (lane & 48) | ((lg * 4 + 2) & 15));
        float l3 = __shfl(lsum, (lane & 48) | ((lg * 4 + 3) & 15));
        float inv[4] = {1.0f / l0, 1.0f / l1, 1.0f / l2, 1.0f / l3};
#pragma unroll
        for (int r = 0; r < 4; r++) {
            int tok = qb + lg * 4 + r;
            __hip_bfloat16* crow = ctx + ((size_t)(bb * 2048 + tok)) * 1024 + h * 64;
#pragma unroll
            for (int n = 0; n < 4; n++) crow[n * 16 + lr] = __float2bfloat16(o[n][r] * inv[r]);
        }
    }
}

// ---------------- output projection GEMM (128x64 tile) ----------------
__global__ __launch_bounds__(256) void gemm_out(const __hip_bfloat16* __restrict__ A,
                                                const __hip_bfloat16* __restrict__ B,
                                                const float* __restrict__ bias,
                                                float* __restrict__ out) {
    constexpr int K = 1024;
    __shared__ __hip_bfloat16 smem[2][128 * 32 + 64 * 32];
    const int tid = threadIdx.x;
    const int lane = tid & 63, wid = tid >> 6;
    const int wr = wid >> 1, wc = wid & 1;
    const int lr = lane & 15, lg = lane >> 4;
    const int m0 = blockIdx.y * 128;
    const int n0 = blockIdx.x * 64;

    const f32x4 fz = {0.f, 0.f, 0.f, 0.f};
    f32x4 acc[4][2];
#pragma unroll
    for (int i = 0; i < 4; i++)
#pragma unroll
        for (int j = 0; j < 2; j++) acc[i][j] = fz;

    const char* Abase = (const char*)A + (size_t)m0 * K * 2;
    const char* Bbase = (const char*)B + (size_t)n0 * K * 2;

    auto stage = [&](int buf, int kt) {
        const int kb = kt * 64;
        char* sA = (char*)&smem[buf][0];
        char* sB = (char*)&smem[buf][128 * 32];
#pragma unroll
        for (int i = 0; i < 2; i++) {
            int o = i * 4096 + tid * 16;
            int row = o >> 6, cb = o & 63;
            __builtin_amdgcn_global_load_lds(GAS(Abase + (size_t)row * 2048 + kb + cb),
                                             LAS(sA + o), 16, 0, 0);
        }
        {
            int o = tid * 16;
            int row = o >> 6, cb = o & 63;
            __builtin_amdgcn_global_load_lds(GAS(Bbase + (size_t)row * 2048 + kb + cb),
                                             LAS(sB + o), 16, 0, 0);
        }
    };

    stage(0, 0);
    __syncthreads();
    int buf = 0;
    constexpr int NT = K / 32;
    for (int kt = 0; kt < NT; ++kt) {
        if (kt + 1 < NT) stage(buf ^ 1, kt + 1);
        const __hip_bfloat16* sA = &smem[buf][0];
        const __hip_bfloat16* sB = &smem[buf][128 * 32];
        short8 a[4], b[2];
#pragma unroll
        for (int i = 0; i < 4; i++)
            a[i] = *reinterpret_cast<const short8*>(sA + (wr * 64 + i * 16 + lr) * 32 + lg * 8);
#pragma unroll
        for (int j = 0; j < 2; j++)
            b[j] = *reinterpret_cast<const short8*>(sB + (wc * 32 + j * 16 + lr) * 32 + lg * 8);
#pragma unroll
        for (int i = 0; i < 4; i++)
#pragma unroll
            for (int j = 0; j < 2; j++)
                acc[i][j] = __builtin_amdgcn_mfma_f32_16x16x32_bf16(a[i], b[j], acc[i][j], 0, 0, 0);
        __syncthreads();
        buf ^= 1;
    }

#pragma unroll
    for (int j = 0; j < 2; j++) {
        int e = n0 + wc * 32 + j * 16 + lr;
        float bv = bias[e];
#pragma unroll
        for (int i = 0; i < 4; i++) {
            int mb = m0 + wr * 64 + i * 16 + lg * 4;
#pragma unroll
            for (int r = 0; r < 4; r++) {
                out[(size_t)(mb + r) * 1024 + e] = acc[i][j][r] + bv;
            }
        }
    }
}

extern "C" void kernel_launch(void* const* d_in, const int* in_sizes, int n_in,
                              void* d_out, int out_size, void* d_ws, size_t ws_size,
                              hipStream_t stream) {
    const float* x = (const float*)d_in[0];
    const float* w_in = (const float*)d_in[1];
    const float* b_in = (const float*)d_in[2];
    const float* w_out = (const float*)d_in[3];
    const float* b_out = (const float*)d_in[4];
    float* out = (float*)d_out;

    char* ws = (char*)d_ws;
    __hip_bfloat16* xbf  = (__hip_bfloat16*)(ws);
    __hip_bfloat16* wbf  = (__hip_bfloat16*)(ws + (8ull << 20));
    __hip_bfloat16* owbf = (__hip_bfloat16*)(ws + (14ull << 20));
    __hip_bfloat16* Qb   = (__hip_bfloat16*)(ws + (16ull << 20));
    __hip_bfloat16* Kb   = (__hip_bfloat16*)(ws + (24ull << 20));
    __hip_bfloat16* Vb   = (__hip_bfloat16*)(ws + (32ull << 20));
    __hip_bfloat16* Vt   = (__hip_bfloat16*)(ws + (40ull << 20));
    __hip_bfloat16* ctxb = (__hip_bfloat16*)(ws + (48ull << 20));

    cvt_bf16<<<2048, 256, 0, stream>>>(x, (short*)xbf, 4194304);
    cvt_bf16<<<1536, 256, 0, stream>>>(w_in, (short*)wbf, 3145728);
    cvt_bf16<<<512, 256, 0, stream>>>(w_out, (short*)owbf, 1048576);
    gemm_qkv<<<dim3(24, 32), 256, 0, stream>>>(xbf, wbf, b_in, Qb, Kb, Vb);
    transpose_v<<<dim3(32, 32), 256, 0, stream>>>(Vb, Vt);
    attn<<<dim3(16, 32), 256, 0, stream>>>(Qb, Kb, Vt, ctxb);
    gemm_out<<<dim3(16, 32), 256, 0, stream>>>(ctxb, owbf, b_out, out);
}

// Round 3
// 192.744 us; speedup vs baseline: 1.3690x; 1.0349x over previous
//
#include <hip/hip_runtime.h>
#include <hip/hip_bf16.h>

typedef __attribute__((ext_vector_type(8))) short short8;   // 8 bf16 = 16B
typedef __attribute__((ext_vector_type(4))) short short4v;  // 4 bf16 = 8B
typedef __attribute__((ext_vector_type(4))) float f32x4;

#define GAS(p) ((const __attribute__((address_space(1))) void*)(p))
#define LAS(p) ((__attribute__((address_space(3))) void*)(p))

__device__ __forceinline__ short f2bf_bits(float f) {
    __hip_bfloat16 h = __float2bfloat16(f);
    return *reinterpret_cast<short*>(&h);
}

// ---------------- fp32 -> bf16 conversion, all three tensors in one launch --
__global__ __launch_bounds__(256) void cvt_all(const float* __restrict__ x,
                                               const float* __restrict__ w1,
                                               const float* __restrict__ w2,
                                               short* __restrict__ dx,
                                               short* __restrict__ dw1,
                                               short* __restrict__ dw2) {
    constexpr int N1 = 4194304, N2 = 3145728;   // x, w_in; w_out = 1048576
    int i = (blockIdx.x * 256 + threadIdx.x) * 8;
    const float* src; short* dst; int j;
    if (i < N1)            { src = x;  dst = dx;  j = i; }
    else if (i < N1 + N2)  { src = w1; dst = dw1; j = i - N1; }
    else                   { src = w2; dst = dw2; j = i - N1 - N2; }
    float4 a = *reinterpret_cast<const float4*>(src + j);
    float4 b = *reinterpret_cast<const float4*>(src + j + 4);
    short8 o;
    o[0] = f2bf_bits(a.x); o[1] = f2bf_bits(a.y);
    o[2] = f2bf_bits(a.z); o[3] = f2bf_bits(a.w);
    o[4] = f2bf_bits(b.x); o[5] = f2bf_bits(b.y);
    o[6] = f2bf_bits(b.z); o[7] = f2bf_bits(b.w);
    *reinterpret_cast<short8*>(dst + j) = o;
}

// ---------------- QKV projection GEMM ----------------
__global__ __launch_bounds__(256) void gemm_qkv(const __hip_bfloat16* __restrict__ A,
                                                const __hip_bfloat16* __restrict__ B,
                                                const float* __restrict__ bias,
                                                __hip_bfloat16* __restrict__ Qb,
                                                __hip_bfloat16* __restrict__ Kb,
                                                __hip_bfloat16* __restrict__ Vb) {
    constexpr int K = 1024;
    __shared__ __hip_bfloat16 smem[2][128 * 32 + 128 * 32];
    const int tid = threadIdx.x;
    const int lane = tid & 63, wid = tid >> 6;
    const int wr = wid >> 1, wc = wid & 1;
    const int lr = lane & 15, lg = lane >> 4;
    const int m0 = blockIdx.y * 128;
    const int n0 = blockIdx.x * 128;

    const f32x4 fz = {0.f, 0.f, 0.f, 0.f};
    f32x4 acc[4][4];
#pragma unroll
    for (int i = 0; i < 4; i++)
#pragma unroll
        for (int j = 0; j < 4; j++) acc[i][j] = fz;

    const char* Abase = (const char*)A + (size_t)m0 * K * 2;
    const char* Bbase = (const char*)B + (size_t)n0 * K * 2;

    auto stage = [&](int buf, int kt) {
        const int kb = kt * 64;
        char* sA = (char*)&smem[buf][0];
        char* sB = (char*)&smem[buf][128 * 32];
#pragma unroll
        for (int i = 0; i < 2; i++) {
            int o = i * 4096 + tid * 16;
            int row = o >> 6, cb = o & 63;
            __builtin_amdgcn_global_load_lds(GAS(Abase + (size_t)row * 2048 + kb + cb),
                                             LAS(sA + o), 16, 0, 0);
        }
#pragma unroll
        for (int i = 0; i < 2; i++) {
            int o = i * 4096 + tid * 16;
            int row = o >> 6, cb = o & 63;
            __builtin_amdgcn_global_load_lds(GAS(Bbase + (size_t)row * 2048 + kb + cb),
                                             LAS(sB + o), 16, 0, 0);
        }
    };

    stage(0, 0);
    __syncthreads();
    int buf = 0;
    constexpr int NT = K / 32;
    for (int kt = 0; kt < NT; ++kt) {
        if (kt + 1 < NT) stage(buf ^ 1, kt + 1);
        const __hip_bfloat16* sA = &smem[buf][0];
        const __hip_bfloat16* sB = &smem[buf][128 * 32];
        short8 a[4], b[4];
#pragma unroll
        for (int i = 0; i < 4; i++)
            a[i] = *reinterpret_cast<const short8*>(sA + (wr * 64 + i * 16 + lr) * 32 + lg * 8);
#pragma unroll
        for (int j = 0; j < 4; j++)
            b[j] = *reinterpret_cast<const short8*>(sB + (wc * 64 + j * 16 + lr) * 32 + lg * 8);
#pragma unroll
        for (int i = 0; i < 4; i++)
#pragma unroll
            for (int j = 0; j < 4; j++)
                acc[i][j] = __builtin_amdgcn_mfma_f32_16x16x32_bf16(a[i], b[j], acc[i][j], 0, 0, 0);
        __syncthreads();
        buf ^= 1;
    }

#pragma unroll
    for (int j = 0; j < 4; j++) {
        int e = n0 + wc * 64 + j * 16 + lr;
        float bv = bias[e];
        int sec = e >> 10;
        int el = e & 1023;
        int h = el >> 6, d = el & 63;
        __hip_bfloat16* dst = (sec == 0) ? Qb : ((sec == 1) ? Kb : Vb);
        // Q carries 1/sqrt(64) * log2(e) so attention can use exp2 directly
        float scale = (sec == 0) ? 0.18033688011112042f : 1.0f;
#pragma unroll
        for (int i = 0; i < 4; i++) {
            int mb = m0 + wr * 64 + i * 16 + lg * 4;
#pragma unroll
            for (int r = 0; r < 4; r++) {
                int tok = mb + r;
                int bb = tok >> 11, l = tok & 2047;
                float v = (acc[i][j][r] + bv) * scale;
                dst[((size_t)(bb * 16 + h) * 2048 + l) * 64 + d] = __float2bfloat16(v);
            }
        }
    }
}

// ---------------- V transpose: [bh][l][64] -> [bh][64][L] ----------------
__global__ __launch_bounds__(256) void transpose_v(const __hip_bfloat16* __restrict__ V,
                                                   __hip_bfloat16* __restrict__ Vt) {
    __shared__ unsigned short tb[64][72];
    int bh = blockIdx.y, l0 = blockIdx.x * 64;
    int tid = threadIdx.x;
    const unsigned short* src = (const unsigned short*)V + ((size_t)bh * 2048 + l0) * 64;
#pragma unroll
    for (int i = 0; i < 2; i++) {
        int idx = i * 256 + tid;
        int row = idx >> 3;
        int c0 = (idx & 7) * 8;
        short8 v = *reinterpret_cast<const short8*>(src + row * 64 + c0);
#pragma unroll
        for (int jj = 0; jj < 8; jj++) tb[c0 + jj][row] = (unsigned short)v[jj];
    }
    __syncthreads();
    unsigned short* dst = (unsigned short*)Vt + (size_t)bh * 64 * 2048 + l0;
#pragma unroll
    for (int i = 0; i < 2; i++) {
        int idx = i * 256 + tid;
        int d = idx >> 3;
        int c8 = (idx & 7) * 8;
        short8 vv = *reinterpret_cast<const short8*>(&tb[d][c8]);
        *reinterpret_cast<short8*>(dst + (size_t)d * 2048 + c8) = vv;
    }
}

// ---------------- causal flash attention ----------------
// Swapped QK^T (lane owns a q-row), paired q-tiles (uniform 33 iters),
// collapsed LDS addressing (kv&7 == lr&7 -> slot invariant across n),
// exp2 softmax (log2e folded into Q), defer-max rescale, setprio on MFMA.
__global__ __launch_bounds__(256) void attn(const __hip_bfloat16* __restrict__ Qg,
                                            const __hip_bfloat16* __restrict__ Kg,
                                            const __hip_bfloat16* __restrict__ Vtg,
                                            __hip_bfloat16* __restrict__ ctx) {
    const int bh = blockIdx.y;
    const int tid = threadIdx.x, lane = tid & 63, wq = tid >> 6;
    const int lr = lane & 15, lg = lane >> 4;

    __shared__ __hip_bfloat16 Ks[2][64 * 64];    // [kv][dh], swizzled 16B slots
    __shared__ __hip_bfloat16 Vs[2][64 * 64];    // [d][kv],  swizzled 16B slots
    __shared__ __hip_bfloat16 Ps[4][16 * 72];    // per-wave P [q][kv], padded

    const char* kbase = (const char*)Kg + (size_t)bh * (2048 * 64 * 2);
    const char* vbase = (const char*)Vtg + (size_t)bh * (64 * 2048 * 2);
    const int bb = bh >> 4, h = bh & 15;

    // ---- hoisted stage addressing (invariant: (srow+32)&7 == srow&7) ----
    const int srow = tid >> 3;                    // LDS tile row for this thread
    const int ssl = (tid & 7) ^ (srow & 7);       // inverse-swizzled source slot
    const char* gk0 = kbase + srow * 128 + ssl * 16;          // += kt*8192
    const char* gv0 = vbase + (size_t)srow * 4096 + ssl * 16; // += kt*128

    // ---- hoisted fragment-read offsets (slot = lg^(lr&7), same for all n) --
    const int koffA = lr * 64 + ((lg ^ (lr & 7)) * 8);        // + n*1024
    const int koffB = lr * 64 + (((4 + lg) ^ (lr & 7)) * 8);
    __hip_bfloat16* pwW = &Ps[wq][0] + lr * 72 + lg * 4;      // + n*16
    const __hip_bfloat16* pwR = &Ps[wq][0] + lr * 72 + lg * 8; // +0, +32

    auto stage = [&](int buf, int kt) {
        char* dK = (char*)&Ks[buf][0] + tid * 16;
        char* dV = (char*)&Vs[buf][0] + tid * 16;
        const char* srcK = gk0 + (size_t)kt * 8192;
        const char* srcV = gv0 + (size_t)kt * 128;
        __builtin_amdgcn_global_load_lds(GAS(srcK), LAS(dK), 16, 0, 0);
        __builtin_amdgcn_global_load_lds(GAS(srcK + 4096), LAS(dK + 4096), 16, 0, 0);
        __builtin_amdgcn_global_load_lds(GAS(srcV), LAS(dV), 16, 0, 0);
        __builtin_amdgcn_global_load_lds(GAS(srcV + 131072), LAS(dV + 4096), 16, 0, 0);
    };

    const f32x4 fz = {0.f, 0.f, 0.f, 0.f};

#pragma unroll 1
    for (int seg = 0; seg < 2; ++seg) {
        const int qt = (seg == 0) ? (int)blockIdx.x : 31 - (int)blockIdx.x;
        const int qb = qt * 64 + wq * 16;

        const __hip_bfloat16* Qrow = Qg + ((size_t)bh * 2048 + qb + lr) * 64 + lg * 8;
        short8 qf0 = *reinterpret_cast<const short8*>(Qrow);
        short8 qf1 = *reinterpret_cast<const short8*>(Qrow + 32);

        f32x4 o[4];
#pragma unroll
        for (int n = 0; n < 4; n++) o[n] = fz;
        float m = -1e30f, lsum = 0.f;

        const int NT = qt + 1;
        stage(0, 0);
        __syncthreads();
        int buf = 0;
        for (int kt = 0; kt < NT; ++kt) {
            if (kt + 1 < NT) stage(buf ^ 1, kt + 1);
            const __hip_bfloat16* sK = &Ks[buf][0];
            const __hip_bfloat16* sV = &Vs[buf][0];

            // S^T = K Q^T : lane owns q-row lr; kv = n*16 + lg*4 + r
            f32x4 s[4];
#pragma unroll
            for (int n = 0; n < 4; n++) s[n] = fz;
            __builtin_amdgcn_s_setprio(1);
#pragma unroll
            for (int n = 0; n < 4; n++) {
                short8 k0 = *reinterpret_cast<const short8*>(sK + koffA + n * 1024);
                short8 k1 = *reinterpret_cast<const short8*>(sK + koffB + n * 1024);
                s[n] = __builtin_amdgcn_mfma_f32_16x16x32_bf16(k0, qf0, s[n], 0, 0, 0);
                s[n] = __builtin_amdgcn_mfma_f32_16x16x32_bf16(k1, qf1, s[n], 0, 0, 0);
            }
            __builtin_amdgcn_s_setprio(0);

            if (kt == NT - 1) {   // causal mask on the diagonal tile
                int q = qb + lr;
#pragma unroll
                for (int n = 0; n < 4; n++) {
                    int kvb = kt * 64 + n * 16 + lg * 4;
#pragma unroll
                    for (int r = 0; r < 4; r++)
                        if (kvb + r > q) s[n][r] = -1e30f;
                }
            }

            // row max (lane-local + 2 shuffles; replicated across lg groups)
            float mx = fmaxf(fmaxf(fmaxf(s[0][0], s[0][1]), fmaxf(s[0][2], s[0][3])),
                             fmaxf(fmaxf(fmaxf(s[1][0], s[1][1]), fmaxf(s[1][2], s[1][3])),
                                   fmaxf(fmaxf(fmaxf(s[2][0], s[2][1]), fmaxf(s[2][2], s[2][3])),
                                         fmaxf(fmaxf(s[3][0], s[3][1]), fmaxf(s[3][2], s[3][3])))));
            mx = fmaxf(mx, __shfl_xor(mx, 16));
            mx = fmaxf(mx, __shfl_xor(mx, 32));

            // defer-max: only rescale when some row grew by > 8*log2e
            if (!__all(mx - m <= 11.54f)) {
                float mnew = fmaxf(m, mx);
                float corr = __builtin_amdgcn_exp2f(m - mnew);
                m = mnew;
                lsum *= corr;
                float c0 = __shfl(corr, (lane & 48) | (lg * 4 + 0));
                float c1 = __shfl(corr, (lane & 48) | (lg * 4 + 1));
                float c2 = __shfl(corr, (lane & 48) | (lg * 4 + 2));
                float c3 = __shfl(corr, (lane & 48) | (lg * 4 + 3));
#pragma unroll
                for (int n = 0; n < 4; n++) {
                    o[n][0] *= c0; o[n][1] *= c1; o[n][2] *= c2; o[n][3] *= c3;
                }
            }

            // P = 2^(S - m), row-sum
            float psum = 0.f;
#pragma unroll
            for (int n = 0; n < 4; n++) {
                float p0 = __builtin_amdgcn_exp2f(s[n][0] - m);
                float p1 = __builtin_amdgcn_exp2f(s[n][1] - m);
                float p2 = __builtin_amdgcn_exp2f(s[n][2] - m);
                float p3 = __builtin_amdgcn_exp2f(s[n][3] - m);
                s[n][0] = p0; s[n][1] = p1; s[n][2] = p2; s[n][3] = p3;
                psum += (p0 + p1) + (p2 + p3);
            }
            psum += __shfl_xor(psum, 16);
            psum += __shfl_xor(psum, 32);
            lsum += psum;

            // P -> per-wave LDS (A-fragment layout)
#pragma unroll
            for (int n = 0; n < 4; n++) {
                short4v pk;
                pk[0] = f2bf_bits(s[n][0]); pk[1] = f2bf_bits(s[n][1]);
                pk[2] = f2bf_bits(s[n][2]); pk[3] = f2bf_bits(s[n][3]);
                *reinterpret_cast<short4v*>(pwW + n * 16) = pk;
            }
            asm volatile("s_waitcnt lgkmcnt(0)" ::: "memory");
            short8 pa0 = *reinterpret_cast<const short8*>(pwR);
            short8 pa1 = *reinterpret_cast<const short8*>(pwR + 32);

            // PV: O[q][d] += P V  (V fragments reuse koffA/koffB)
            __builtin_amdgcn_s_setprio(1);
#pragma unroll
            for (int n = 0; n < 4; n++) {
                short8 vf0 = *reinterpret_cast<const short8*>(sV + koffA + n * 1024);
                short8 vf1 = *reinterpret_cast<const short8*>(sV + koffB + n * 1024);
                o[n] = __builtin_amdgcn_mfma_f32_16x16x32_bf16(pa0, vf0, o[n], 0, 0, 0);
                o[n] = __builtin_amdgcn_mfma_f32_16x16x32_bf16(pa1, vf1, o[n], 0, 0, 0);
            }
            __builtin_amdgcn_s_setprio(0);
            __syncthreads();
            buf ^= 1;
        }

        // epilogue
        float l0 = __shfl(lsum, (lane & 48) | (lg * 4 + 0));
        float l1 = __shfl(lsum, (lane & 48) | (lg * 4 + 1));
        float l2 = __shfl(lsum, (lane & 48) | (lg * 4 + 2));
        float l3 = __shfl(lsum, (lane & 48) | (lg * 4 + 3));
        float inv[4] = {1.0f / l0, 1.0f / l1, 1.0f / l2, 1.0f / l3};
#pragma unroll
        for (int r = 0; r < 4; r++) {
            int tok = qb + lg * 4 + r;
            __hip_bfloat16* crow = ctx + ((size_t)(bb * 2048 + tok)) * 1024 + h * 64;
#pragma unroll
            for (int n = 0; n < 4; n++) crow[n * 16 + lr] = __float2bfloat16(o[n][r] * inv[r]);
        }
    }
}

// ---------------- output projection GEMM (128x64 tile) ----------------
__global__ __launch_bounds__(256) void gemm_out(const __hip_bfloat16* __restrict__ A,
                                                const __hip_bfloat16* __restrict__ B,
                                                const float* __restrict__ bias,
                                                float* __restrict__ out) {
    constexpr int K = 1024;
    __shared__ __hip_bfloat16 smem[2][128 * 32 + 64 * 32];
    const int tid = threadIdx.x;
    const int lane = tid & 63, wid = tid >> 6;
    const int wr = wid >> 1, wc = wid & 1;
    const int lr = lane & 15, lg = lane >> 4;
    const int m0 = blockIdx.y * 128;
    const int n0 = blockIdx.x * 64;

    const f32x4 fz = {0.f, 0.f, 0.f, 0.f};
    f32x4 acc[4][2];
#pragma unroll
    for (int i = 0; i < 4; i++)
#pragma unroll
        for (int j = 0; j < 2; j++) acc[i][j] = fz;

    const char* Abase = (const char*)A + (size_t)m0 * K * 2;
    const char* Bbase = (const char*)B + (size_t)n0 * K * 2;

    auto stage = [&](int buf, int kt) {
        const int kb = kt * 64;
        char* sA = (char*)&smem[buf][0];
        char* sB = (char*)&smem[buf][128 * 32];
#pragma unroll
        for (int i = 0; i < 2; i++) {
            int o = i * 4096 + tid * 16;
            int row = o >> 6, cb = o & 63;
            __builtin_amdgcn_global_load_lds(GAS(Abase + (size_t)row * 2048 + kb + cb),
                                             LAS(sA + o), 16, 0, 0);
        }
        {
            int o = tid * 16;
            int row = o >> 6, cb = o & 63;
            __builtin_amdgcn_global_load_lds(GAS(Bbase + (size_t)row * 2048 + kb + cb),
                                             LAS(sB + o), 16, 0, 0);
        }
    };

    stage(0, 0);
    __syncthreads();
    int buf = 0;
    constexpr int NT = K / 32;
    for (int kt = 0; kt < NT; ++kt) {
        if (kt + 1 < NT) stage(buf ^ 1, kt + 1);
        const __hip_bfloat16* sA = &smem[buf][0];
        const __hip_bfloat16* sB = &smem[buf][128 * 32];
        short8 a[4], b[2];
#pragma unroll
        for (int i = 0; i < 4; i++)
            a[i] = *reinterpret_cast<const short8*>(sA + (wr * 64 + i * 16 + lr) * 32 + lg * 8);
#pragma unroll
        for (int j = 0; j < 2; j++)
            b[j] = *reinterpret_cast<const short8*>(sB + (wc * 32 + j * 16 + lr) * 32 + lg * 8);
#pragma unroll
        for (int i = 0; i < 4; i++)
#pragma unroll
            for (int j = 0; j < 2; j++)
                acc[i][j] = __builtin_amdgcn_mfma_f32_16x16x32_bf16(a[i], b[j], acc[i][j], 0, 0, 0);
        __syncthreads();
        buf ^= 1;
    }

#pragma unroll
    for (int j = 0; j < 2; j++) {
        int e = n0 + wc * 32 + j * 16 + lr;
        float bv = bias[e];
#pragma unroll
        for (int i = 0; i < 4; i++) {
            int mb = m0 + wr * 64 + i * 16 + lg * 4;
#pragma unroll
            for (int r = 0; r < 4; r++) {
                out[(size_t)(mb + r) * 1024 + e] = acc[i][j][r] + bv;
            }
        }
    }
}

extern "C" void kernel_launch(void* const* d_in, const int* in_sizes, int n_in,
                              void* d_out, int out_size, void* d_ws, size_t ws_size,
                              hipStream_t stream) {
    const float* x = (const float*)d_in[0];
    const float* w_in = (const float*)d_in[1];
    const float* b_in = (const float*)d_in[2];
    const float* w_out = (const float*)d_in[3];
    const float* b_out = (const float*)d_in[4];
    float* out = (float*)d_out;

    char* ws = (char*)d_ws;
    __hip_bfloat16* xbf  = (__hip_bfloat16*)(ws);
    __hip_bfloat16* wbf  = (__hip_bfloat16*)(ws + (8ull << 20));
    __hip_bfloat16* owbf = (__hip_bfloat16*)(ws + (14ull << 20));
    __hip_bfloat16* Qb   = (__hip_bfloat16*)(ws + (16ull << 20));
    __hip_bfloat16* Kb   = (__hip_bfloat16*)(ws + (24ull << 20));
    __hip_bfloat16* Vb   = (__hip_bfloat16*)(ws + (32ull << 20));
    __hip_bfloat16* Vt   = (__hip_bfloat16*)(ws + (40ull << 20));
    __hip_bfloat16* ctxb = (__hip_bfloat16*)(ws + (48ull << 20));

    cvt_all<<<4096, 256, 0, stream>>>(x, w_in, w_out, (short*)xbf, (short*)wbf, (short*)owbf);
    gemm_qkv<<<dim3(24, 32), 256, 0, stream>>>(xbf, wbf, b_in, Qb, Kb, Vb);
    transpose_v<<<dim3(32, 32), 256, 0, stream>>>(Vb, Vt);
    attn<<<dim3(16, 32), 256, 0, stream>>>(Qb, Kb, Vt, ctxb);
    gemm_out<<<dim3(16, 32), 256, 0, stream>>>(ctxb, owbf, b_out, out);
}

// Round 4
// 184.425 us; speedup vs baseline: 1.4307x; 1.0451x over previous
//
#include <hip/hip_runtime.h>
#include <hip/hip_bf16.h>

typedef __attribute__((ext_vector_type(8))) short short8;   // 8 bf16 = 16B
typedef __attribute__((ext_vector_type(4))) short short4v;  // 4 bf16 = 8B
typedef __attribute__((ext_vector_type(4))) float f32x4;

#define GAS(p) ((const __attribute__((address_space(1))) void*)(p))
#define LAS(p) ((__attribute__((address_space(3))) void*)(p))

__device__ __forceinline__ short f2bf_bits(float f) {
    __hip_bfloat16 h = __float2bfloat16(f);
    return *reinterpret_cast<short*>(&h);
}

// ---------------- fp32 -> bf16 conversion, all three tensors in one launch --
__global__ __launch_bounds__(256) void cvt_all(const float* __restrict__ x,
                                               const float* __restrict__ w1,
                                               const float* __restrict__ w2,
                                               short* __restrict__ dx,
                                               short* __restrict__ dw1,
                                               short* __restrict__ dw2) {
    constexpr int N1 = 4194304, N2 = 3145728;   // x, w_in; w_out = 1048576
    int i = (blockIdx.x * 256 + threadIdx.x) * 8;
    const float* src; short* dst; int j;
    if (i < N1)            { src = x;  dst = dx;  j = i; }
    else if (i < N1 + N2)  { src = w1; dst = dw1; j = i - N1; }
    else                   { src = w2; dst = dw2; j = i - N1 - N2; }
    float4 a = *reinterpret_cast<const float4*>(src + j);
    float4 b = *reinterpret_cast<const float4*>(src + j + 4);
    short8 o;
    o[0] = f2bf_bits(a.x); o[1] = f2bf_bits(a.y);
    o[2] = f2bf_bits(a.z); o[3] = f2bf_bits(a.w);
    o[4] = f2bf_bits(b.x); o[5] = f2bf_bits(b.y);
    o[6] = f2bf_bits(b.z); o[7] = f2bf_bits(b.w);
    *reinterpret_cast<short8*>(dst + j) = o;
}

// ---------------- QKV projection GEMM ----------------
// 1D grid 768, XCD-chunked: xcd = bid&7 handles a 12(bx) x 8(by) tile block
// -> per-XCD L2 working set ~5MB instead of thrashing all of B.
__global__ __launch_bounds__(256) void gemm_qkv(const __hip_bfloat16* __restrict__ A,
                                                const __hip_bfloat16* __restrict__ B,
                                                const float* __restrict__ bias,
                                                __hip_bfloat16* __restrict__ Qb,
                                                __hip_bfloat16* __restrict__ Kb,
                                                __hip_bfloat16* __restrict__ Vb) {
    constexpr int K = 1024;
    __shared__ __hip_bfloat16 smem[2][128 * 32 + 128 * 32];
    const int tid = threadIdx.x;
    const int lane = tid & 63, wid = tid >> 6;
    const int wr = wid >> 1, wc = wid & 1;
    const int lr = lane & 15, lg = lane >> 4;

    const int bid = blockIdx.x;
    const int xcd = bid & 7, w = bid >> 3;         // w in [0,96)
    const int bx = (xcd & 1) * 12 + (w % 12);      // [0,24)
    const int by = (xcd >> 1) * 8 + (w / 12);      // [0,32)
    const int m0 = by * 128;
    const int n0 = bx * 128;

    const f32x4 fz = {0.f, 0.f, 0.f, 0.f};
    f32x4 acc[4][4];
#pragma unroll
    for (int i = 0; i < 4; i++)
#pragma unroll
        for (int j = 0; j < 4; j++) acc[i][j] = fz;

    const char* Abase = (const char*)A + (size_t)m0 * K * 2;
    const char* Bbase = (const char*)B + (size_t)n0 * K * 2;

    auto stage = [&](int buf, int kt) {
        const int kb = kt * 64;
        char* sA = (char*)&smem[buf][0];
        char* sB = (char*)&smem[buf][128 * 32];
#pragma unroll
        for (int i = 0; i < 2; i++) {
            int o = i * 4096 + tid * 16;
            int row = o >> 6, cb = o & 63;
            __builtin_amdgcn_global_load_lds(GAS(Abase + (size_t)row * 2048 + kb + cb),
                                             LAS(sA + o), 16, 0, 0);
        }
#pragma unroll
        for (int i = 0; i < 2; i++) {
            int o = i * 4096 + tid * 16;
            int row = o >> 6, cb = o & 63;
            __builtin_amdgcn_global_load_lds(GAS(Bbase + (size_t)row * 2048 + kb + cb),
                                             LAS(sB + o), 16, 0, 0);
        }
    };

    stage(0, 0);
    __syncthreads();
    int buf = 0;
    constexpr int NT = K / 32;
    for (int kt = 0; kt < NT; ++kt) {
        if (kt + 1 < NT) stage(buf ^ 1, kt + 1);
        const __hip_bfloat16* sA = &smem[buf][0];
        const __hip_bfloat16* sB = &smem[buf][128 * 32];
        short8 a[4], b[4];
#pragma unroll
        for (int i = 0; i < 4; i++)
            a[i] = *reinterpret_cast<const short8*>(sA + (wr * 64 + i * 16 + lr) * 32 + lg * 8);
#pragma unroll
        for (int j = 0; j < 4; j++)
            b[j] = *reinterpret_cast<const short8*>(sB + (wc * 64 + j * 16 + lr) * 32 + lg * 8);
#pragma unroll
        for (int i = 0; i < 4; i++)
#pragma unroll
            for (int j = 0; j < 4; j++)
                acc[i][j] = __builtin_amdgcn_mfma_f32_16x16x32_bf16(a[i], b[j], acc[i][j], 0, 0, 0);
        __syncthreads();
        buf ^= 1;
    }

#pragma unroll
    for (int j = 0; j < 4; j++) {
        int e = n0 + wc * 64 + j * 16 + lr;
        float bv = bias[e];
        int sec = e >> 10;
        int el = e & 1023;
        int h = el >> 6, d = el & 63;
        __hip_bfloat16* dst = (sec == 0) ? Qb : ((sec == 1) ? Kb : Vb);
        // Q carries 1/sqrt(64) * log2(e) so attention can use exp2 directly
        float scale = (sec == 0) ? 0.18033688011112042f : 1.0f;
#pragma unroll
        for (int i = 0; i < 4; i++) {
            int mb = m0 + wr * 64 + i * 16 + lg * 4;
#pragma unroll
            for (int r = 0; r < 4; r++) {
                int tok = mb + r;
                int bb = tok >> 11, l = tok & 2047;
                float v = (acc[i][j][r] + bv) * scale;
                dst[((size_t)(bb * 16 + h) * 2048 + l) * 64 + d] = __float2bfloat16(v);
            }
        }
    }
}

// ---------------- V transpose: [bh][l][64] -> [bh][64][L] ----------------
__global__ __launch_bounds__(256) void transpose_v(const __hip_bfloat16* __restrict__ V,
                                                   __hip_bfloat16* __restrict__ Vt) {
    __shared__ unsigned short tb[64][72];
    int bh = blockIdx.y, l0 = blockIdx.x * 64;
    int tid = threadIdx.x;
    const unsigned short* src = (const unsigned short*)V + ((size_t)bh * 2048 + l0) * 64;
#pragma unroll
    for (int i = 0; i < 2; i++) {
        int idx = i * 256 + tid;
        int row = idx >> 3;
        int c0 = (idx & 7) * 8;
        short8 v = *reinterpret_cast<const short8*>(src + row * 64 + c0);
#pragma unroll
        for (int jj = 0; jj < 8; jj++) tb[c0 + jj][row] = (unsigned short)v[jj];
    }
    __syncthreads();
    unsigned short* dst = (unsigned short*)Vt + (size_t)bh * 64 * 2048 + l0;
#pragma unroll
    for (int i = 0; i < 2; i++) {
        int idx = i * 256 + tid;
        int d = idx >> 3;
        int c8 = (idx & 7) * 8;
        short8 vv = *reinterpret_cast<const short8*>(&tb[d][c8]);
        *reinterpret_cast<short8*>(dst + (size_t)d * 2048 + c8) = vv;
    }
}

// ---------------- causal flash attention ----------------
// XCD-pinned: bid&7 = XCD; each XCD owns 4 bh -> KV+Q working set 3MB < 4MB L2.
// Swapped QK^T, paired q-tiles (uniform 33 iters), collapsed LDS addressing,
// exp2 softmax, defer-max rescale, setprio on MFMA.
__global__ __launch_bounds__(256) void attn(const __hip_bfloat16* __restrict__ Qg,
                                            const __hip_bfloat16* __restrict__ Kg,
                                            const __hip_bfloat16* __restrict__ Vtg,
                                            __hip_bfloat16* __restrict__ ctx) {
    const int bid = blockIdx.x;
    const int xcd = bid & 7, seq = bid >> 3;       // seq in [0,64)
    const int bh = (xcd << 2) | (seq >> 4);        // 4 bh per XCD
    const int qtp = seq & 15;                      // pair index
    const int tid = threadIdx.x, lane = tid & 63, wq = tid >> 6;
    const int lr = lane & 15, lg = lane >> 4;

    __shared__ __hip_bfloat16 Ks[2][64 * 64];    // [kv][dh], swizzled 16B slots
    __shared__ __hip_bfloat16 Vs[2][64 * 64];    // [d][kv],  swizzled 16B slots
    __shared__ __hip_bfloat16 Ps[4][16 * 72];    // per-wave P [q][kv], padded

    const char* kbase = (const char*)Kg + (size_t)bh * (2048 * 64 * 2);
    const char* vbase = (const char*)Vtg + (size_t)bh * (64 * 2048 * 2);
    const int bb = bh >> 4, h = bh & 15;

    // ---- hoisted stage addressing (invariant: (srow+32)&7 == srow&7) ----
    const int srow = tid >> 3;
    const int ssl = (tid & 7) ^ (srow & 7);
    const char* gk0 = kbase + srow * 128 + ssl * 16;          // += kt*8192
    const char* gv0 = vbase + (size_t)srow * 4096 + ssl * 16; // += kt*128

    // ---- hoisted fragment-read offsets (slot = lg^(lr&7), same for all n) --
    const int koffA = lr * 64 + ((lg ^ (lr & 7)) * 8);        // + n*1024
    const int koffB = lr * 64 + (((4 + lg) ^ (lr & 7)) * 8);
    __hip_bfloat16* pwW = &Ps[wq][0] + lr * 72 + lg * 4;      // + n*16
    const __hip_bfloat16* pwR = &Ps[wq][0] + lr * 72 + lg * 8; // +0, +32

    auto stage = [&](int buf, int kt) {
        char* dK = (char*)&Ks[buf][0] + tid * 16;
        char* dV = (char*)&Vs[buf][0] + tid * 16;
        const char* srcK = gk0 + (size_t)kt * 8192;
        const char* srcV = gv0 + (size_t)kt * 128;
        __builtin_amdgcn_global_load_lds(GAS(srcK), LAS(dK), 16, 0, 0);
        __builtin_amdgcn_global_load_lds(GAS(srcK + 4096), LAS(dK + 4096), 16, 0, 0);
        __builtin_amdgcn_global_load_lds(GAS(srcV), LAS(dV), 16, 0, 0);
        __builtin_amdgcn_global_load_lds(GAS(srcV + 131072), LAS(dV + 4096), 16, 0, 0);
    };

    const f32x4 fz = {0.f, 0.f, 0.f, 0.f};

#pragma unroll 1
    for (int seg = 0; seg < 2; ++seg) {
        const int qt = (seg == 0) ? qtp : 31 - qtp;
        const int qb = qt * 64 + wq * 16;

        const __hip_bfloat16* Qrow = Qg + ((size_t)bh * 2048 + qb + lr) * 64 + lg * 8;
        short8 qf0 = *reinterpret_cast<const short8*>(Qrow);
        short8 qf1 = *reinterpret_cast<const short8*>(Qrow + 32);

        f32x4 o[4];
#pragma unroll
        for (int n = 0; n < 4; n++) o[n] = fz;
        float m = -1e30f, lsum = 0.f;

        const int NT = qt + 1;
        stage(0, 0);
        __syncthreads();
        int buf = 0;
        for (int kt = 0; kt < NT; ++kt) {
            if (kt + 1 < NT) stage(buf ^ 1, kt + 1);
            const __hip_bfloat16* sK = &Ks[buf][0];
            const __hip_bfloat16* sV = &Vs[buf][0];

            // S^T = K Q^T : lane owns q-row lr; kv = n*16 + lg*4 + r
            f32x4 s[4];
#pragma unroll
            for (int n = 0; n < 4; n++) s[n] = fz;
            __builtin_amdgcn_s_setprio(1);
#pragma unroll
            for (int n = 0; n < 4; n++) {
                short8 k0 = *reinterpret_cast<const short8*>(sK + koffA + n * 1024);
                short8 k1 = *reinterpret_cast<const short8*>(sK + koffB + n * 1024);
                s[n] = __builtin_amdgcn_mfma_f32_16x16x32_bf16(k0, qf0, s[n], 0, 0, 0);
                s[n] = __builtin_amdgcn_mfma_f32_16x16x32_bf16(k1, qf1, s[n], 0, 0, 0);
            }
            __builtin_amdgcn_s_setprio(0);

            if (kt == NT - 1) {   // causal mask on the diagonal tile
                int q = qb + lr;
#pragma unroll
                for (int n = 0; n < 4; n++) {
                    int kvb = kt * 64 + n * 16 + lg * 4;
#pragma unroll
                    for (int r = 0; r < 4; r++)
                        if (kvb + r > q) s[n][r] = -1e30f;
                }
            }

            // row max (lane-local + 2 shuffles)
            float mx = fmaxf(fmaxf(fmaxf(s[0][0], s[0][1]), fmaxf(s[0][2], s[0][3])),
                             fmaxf(fmaxf(fmaxf(s[1][0], s[1][1]), fmaxf(s[1][2], s[1][3])),
                                   fmaxf(fmaxf(fmaxf(s[2][0], s[2][1]), fmaxf(s[2][2], s[2][3])),
                                         fmaxf(fmaxf(s[3][0], s[3][1]), fmaxf(s[3][2], s[3][3])))));
            mx = fmaxf(mx, __shfl_xor(mx, 16));
            mx = fmaxf(mx, __shfl_xor(mx, 32));

            // defer-max: only rescale when some row grew by > 8*log2e
            if (!__all(mx - m <= 11.54f)) {
                float mnew = fmaxf(m, mx);
                float corr = __builtin_amdgcn_exp2f(m - mnew);
                m = mnew;
                lsum *= corr;
                float c0 = __shfl(corr, (lane & 48) | (lg * 4 + 0));
                float c1 = __shfl(corr, (lane & 48) | (lg * 4 + 1));
                float c2 = __shfl(corr, (lane & 48) | (lg * 4 + 2));
                float c3 = __shfl(corr, (lane & 48) | (lg * 4 + 3));
#pragma unroll
                for (int n = 0; n < 4; n++) {
                    o[n][0] *= c0; o[n][1] *= c1; o[n][2] *= c2; o[n][3] *= c3;
                }
            }

            // P = 2^(S - m), row-sum
            float psum = 0.f;
#pragma unroll
            for (int n = 0; n < 4; n++) {
                float p0 = __builtin_amdgcn_exp2f(s[n][0] - m);
                float p1 = __builtin_amdgcn_exp2f(s[n][1] - m);
                float p2 = __builtin_amdgcn_exp2f(s[n][2] - m);
                float p3 = __builtin_amdgcn_exp2f(s[n][3] - m);
                s[n][0] = p0; s[n][1] = p1; s[n][2] = p2; s[n][3] = p3;
                psum += (p0 + p1) + (p2 + p3);
            }
            psum += __shfl_xor(psum, 16);
            psum += __shfl_xor(psum, 32);
            lsum += psum;

            // P -> per-wave LDS (A-fragment layout)
#pragma unroll
            for (int n = 0; n < 4; n++) {
                short4v pk;
                pk[0] = f2bf_bits(s[n][0]); pk[1] = f2bf_bits(s[n][1]);
                pk[2] = f2bf_bits(s[n][2]); pk[3] = f2bf_bits(s[n][3]);
                *reinterpret_cast<short4v*>(pwW + n * 16) = pk;
            }
            asm volatile("s_waitcnt lgkmcnt(0)" ::: "memory");
            short8 pa0 = *reinterpret_cast<const short8*>(pwR);
            short8 pa1 = *reinterpret_cast<const short8*>(pwR + 32);

            // PV: O[q][d] += P V  (V fragments reuse koffA/koffB)
            __builtin_amdgcn_s_setprio(1);
#pragma unroll
            for (int n = 0; n < 4; n++) {
                short8 vf0 = *reinterpret_cast<const short8*>(sV + koffA + n * 1024);
                short8 vf1 = *reinterpret_cast<const short8*>(sV + koffB + n * 1024);
                o[n] = __builtin_amdgcn_mfma_f32_16x16x32_bf16(pa0, vf0, o[n], 0, 0, 0);
                o[n] = __builtin_amdgcn_mfma_f32_16x16x32_bf16(pa1, vf1, o[n], 0, 0, 0);
            }
            __builtin_amdgcn_s_setprio(0);
            __syncthreads();
            buf ^= 1;
        }

        // epilogue
        float l0 = __shfl(lsum, (lane & 48) | (lg * 4 + 0));
        float l1 = __shfl(lsum, (lane & 48) | (lg * 4 + 1));
        float l2 = __shfl(lsum, (lane & 48) | (lg * 4 + 2));
        float l3 = __shfl(lsum, (lane & 48) | (lg * 4 + 3));
        float inv[4] = {1.0f / l0, 1.0f / l1, 1.0f / l2, 1.0f / l3};
#pragma unroll
        for (int r = 0; r < 4; r++) {
            int tok = qb + lg * 4 + r;
            __hip_bfloat16* crow = ctx + ((size_t)(bb * 2048 + tok)) * 1024 + h * 64;
#pragma unroll
            for (int n = 0; n < 4; n++) crow[n * 16 + lr] = __float2bfloat16(o[n][r] * inv[r]);
        }
    }
}

// ---------------- output projection GEMM (128x64 tile) ----------------
// 1D grid 512, XCD-chunked: per XCD 16(bx) x 4(by) -> ~3MB L2 working set.
__global__ __launch_bounds__(256) void gemm_out(const __hip_bfloat16* __restrict__ A,
                                                const __hip_bfloat16* __restrict__ B,
                                                const float* __restrict__ bias,
                                                float* __restrict__ out) {
    constexpr int K = 1024;
    __shared__ __hip_bfloat16 smem[2][128 * 32 + 64 * 32];
    const int tid = threadIdx.x;
    const int lane = tid & 63, wid = tid >> 6;
    const int wr = wid >> 1, wc = wid & 1;
    const int lr = lane & 15, lg = lane >> 4;

    const int bid = blockIdx.x;
    const int xcd = bid & 7, w = bid >> 3;     // w in [0,64)
    const int bx = w & 15;                     // [0,16)
    const int by = (xcd << 2) | (w >> 4);      // [0,32)
    const int m0 = by * 128;
    const int n0 = bx * 64;

    const f32x4 fz = {0.f, 0.f, 0.f, 0.f};
    f32x4 acc[4][2];
#pragma unroll
    for (int i = 0; i < 4; i++)
#pragma unroll
        for (int j = 0; j < 2; j++) acc[i][j] = fz;

    const char* Abase = (const char*)A + (size_t)m0 * K * 2;
    const char* Bbase = (const char*)B + (size_t)n0 * K * 2;

    auto stage = [&](int buf, int kt) {
        const int kb = kt * 64;
        char* sA = (char*)&smem[buf][0];
        char* sB = (char*)&smem[buf][128 * 32];
#pragma unroll
        for (int i = 0; i < 2; i++) {
            int o = i * 4096 + tid * 16;
            int row = o >> 6, cb = o & 63;
            __builtin_amdgcn_global_load_lds(GAS(Abase + (size_t)row * 2048 + kb + cb),
                                             LAS(sA + o), 16, 0, 0);
        }
        {
            int o = tid * 16;
            int row = o >> 6, cb = o & 63;
            __builtin_amdgcn_global_load_lds(GAS(Bbase + (size_t)row * 2048 + kb + cb),
                                             LAS(sB + o), 16, 0, 0);
        }
    };

    stage(0, 0);
    __syncthreads();
    int buf = 0;
    constexpr int NT = K / 32;
    for (int kt = 0; kt < NT; ++kt) {
        if (kt + 1 < NT) stage(buf ^ 1, kt + 1);
        const __hip_bfloat16* sA = &smem[buf][0];
        const __hip_bfloat16* sB = &smem[buf][128 * 32];
        short8 a[4], b[2];
#pragma unroll
        for (int i = 0; i < 4; i++)
            a[i] = *reinterpret_cast<const short8*>(sA + (wr * 64 + i * 16 + lr) * 32 + lg * 8);
#pragma unroll
        for (int j = 0; j < 2; j++)
            b[j] = *reinterpret_cast<const short8*>(sB + (wc * 32 + j * 16 + lr) * 32 + lg * 8);
#pragma unroll
        for (int i = 0; i < 4; i++)
#pragma unroll
            for (int j = 0; j < 2; j++)
                acc[i][j] = __builtin_amdgcn_mfma_f32_16x16x32_bf16(a[i], b[j], acc[i][j], 0, 0, 0);
        __syncthreads();
        buf ^= 1;
    }

#pragma unroll
    for (int j = 0; j < 2; j++) {
        int e = n0 + wc * 32 + j * 16 + lr;
        float bv = bias[e];
#pragma unroll
        for (int i = 0; i < 4; i++) {
            int mb = m0 + wr * 64 + i * 16 + lg * 4;
#pragma unroll
            for (int r = 0; r < 4; r++) {
                out[(size_t)(mb + r) * 1024 + e] = acc[i][j][r] + bv;
            }
        }
    }
}

extern "C" void kernel_launch(void* const* d_in, const int* in_sizes, int n_in,
                              void* d_out, int out_size, void* d_ws, size_t ws_size,
                              hipStream_t stream) {
    const float* x = (const float*)d_in[0];
    const float* w_in = (const float*)d_in[1];
    const float* b_in = (const float*)d_in[2];
    const float* w_out = (const float*)d_in[3];
    const float* b_out = (const float*)d_in[4];
    float* out = (float*)d_out;

    char* ws = (char*)d_ws;
    __hip_bfloat16* xbf  = (__hip_bfloat16*)(ws);
    __hip_bfloat16* wbf  = (__hip_bfloat16*)(ws + (8ull << 20));
    __hip_bfloat16* owbf = (__hip_bfloat16*)(ws + (14ull << 20));
    __hip_bfloat16* Qb   = (__hip_bfloat16*)(ws + (16ull << 20));
    __hip_bfloat16* Kb   = (__hip_bfloat16*)(ws + (24ull << 20));
    __hip_bfloat16* Vb   = (__hip_bfloat16*)(ws + (32ull << 20));
    __hip_bfloat16* Vt   = (__hip_bfloat16*)(ws + (40ull << 20));
    __hip_bfloat16* ctxb = (__hip_bfloat16*)(ws + (48ull << 20));

    cvt_all<<<4096, 256, 0, stream>>>(x, w_in, w_out, (short*)xbf, (short*)wbf, (short*)owbf);
    gemm_qkv<<<768, 256, 0, stream>>>(xbf, wbf, b_in, Qb, Kb, Vb);
    transpose_v<<<dim3(32, 32), 256, 0, stream>>>(Vb, Vt);
    attn<<<512, 256, 0, stream>>>(Qb, Kb, Vt, ctxb);
    gemm_out<<<512, 256, 0, stream>>>(ctxb, owbf, b_out, out);
}

// Round 5
// 180.572 us; speedup vs baseline: 1.4613x; 1.0213x over previous
//
#include <hip/hip_runtime.h>
#include <hip/hip_bf16.h>

typedef __attribute__((ext_vector_type(8))) short short8;   // 8 bf16 = 16B
typedef __attribute__((ext_vector_type(4))) short short4v;  // 4 bf16 = 8B
typedef __attribute__((ext_vector_type(4))) float f32x4;

#define GAS(p) ((const __attribute__((address_space(1))) void*)(p))
#define LAS(p) ((__attribute__((address_space(3))) void*)(p))

__device__ __forceinline__ short f2bf_bits(float f) {
    __hip_bfloat16 h = __float2bfloat16(f);
    return *reinterpret_cast<short*>(&h);
}

// ---------------- fp32 -> bf16 conversion, all three tensors in one launch --
__global__ __launch_bounds__(256) void cvt_all(const float* __restrict__ x,
                                               const float* __restrict__ w1,
                                               const float* __restrict__ w2,
                                               short* __restrict__ dx,
                                               short* __restrict__ dw1,
                                               short* __restrict__ dw2) {
    constexpr int N1 = 4194304, N2 = 3145728;   // x, w_in; w_out = 1048576
    int i = (blockIdx.x * 256 + threadIdx.x) * 8;
    const float* src; short* dst; int j;
    if (i < N1)            { src = x;  dst = dx;  j = i; }
    else if (i < N1 + N2)  { src = w1; dst = dw1; j = i - N1; }
    else                   { src = w2; dst = dw2; j = i - N1 - N2; }
    float4 a = *reinterpret_cast<const float4*>(src + j);
    float4 b = *reinterpret_cast<const float4*>(src + j + 4);
    short8 o;
    o[0] = f2bf_bits(a.x); o[1] = f2bf_bits(a.y);
    o[2] = f2bf_bits(a.z); o[3] = f2bf_bits(a.w);
    o[4] = f2bf_bits(b.x); o[5] = f2bf_bits(b.y);
    o[6] = f2bf_bits(b.z); o[7] = f2bf_bits(b.w);
    *reinterpret_cast<short8*>(dst + j) = o;
}

// ---------------- QKV projection GEMM ----------------
// 1D grid 768, XCD-chunked: xcd = bid&7 handles a 12(bx) x 8(by) tile block
// -> per-XCD L2 working set ~5MB instead of thrashing all of B.
__global__ __launch_bounds__(256) void gemm_qkv(const __hip_bfloat16* __restrict__ A,
                                                const __hip_bfloat16* __restrict__ B,
                                                const float* __restrict__ bias,
                                                __hip_bfloat16* __restrict__ Qb,
                                                __hip_bfloat16* __restrict__ Kb,
                                                __hip_bfloat16* __restrict__ Vb) {
    constexpr int K = 1024;
    __shared__ __hip_bfloat16 smem[2][128 * 32 + 128 * 32];
    const int tid = threadIdx.x;
    const int lane = tid & 63, wid = tid >> 6;
    const int wr = wid >> 1, wc = wid & 1;
    const int lr = lane & 15, lg = lane >> 4;

    const int bid = blockIdx.x;
    const int xcd = bid & 7, w = bid >> 3;         // w in [0,96)
    const int bx = (xcd & 1) * 12 + (w % 12);      // [0,24)
    const int by = (xcd >> 1) * 8 + (w / 12);      // [0,32)
    const int m0 = by * 128;
    const int n0 = bx * 128;

    const f32x4 fz = {0.f, 0.f, 0.f, 0.f};
    f32x4 acc[4][4];
#pragma unroll
    for (int i = 0; i < 4; i++)
#pragma unroll
        for (int j = 0; j < 4; j++) acc[i][j] = fz;

    const char* Abase = (const char*)A + (size_t)m0 * K * 2;
    const char* Bbase = (const char*)B + (size_t)n0 * K * 2;

    auto stage = [&](int buf, int kt) {
        const int kb = kt * 64;
        char* sA = (char*)&smem[buf][0];
        char* sB = (char*)&smem[buf][128 * 32];
#pragma unroll
        for (int i = 0; i < 2; i++) {
            int o = i * 4096 + tid * 16;
            int row = o >> 6, cb = o & 63;
            __builtin_amdgcn_global_load_lds(GAS(Abase + (size_t)row * 2048 + kb + cb),
                                             LAS(sA + o), 16, 0, 0);
        }
#pragma unroll
        for (int i = 0; i < 2; i++) {
            int o = i * 4096 + tid * 16;
            int row = o >> 6, cb = o & 63;
            __builtin_amdgcn_global_load_lds(GAS(Bbase + (size_t)row * 2048 + kb + cb),
                                             LAS(sB + o), 16, 0, 0);
        }
    };

    stage(0, 0);
    __syncthreads();
    int buf = 0;
    constexpr int NT = K / 32;
    for (int kt = 0; kt < NT; ++kt) {
        if (kt + 1 < NT) stage(buf ^ 1, kt + 1);
        const __hip_bfloat16* sA = &smem[buf][0];
        const __hip_bfloat16* sB = &smem[buf][128 * 32];
        short8 a[4], b[4];
#pragma unroll
        for (int i = 0; i < 4; i++)
            a[i] = *reinterpret_cast<const short8*>(sA + (wr * 64 + i * 16 + lr) * 32 + lg * 8);
#pragma unroll
        for (int j = 0; j < 4; j++)
            b[j] = *reinterpret_cast<const short8*>(sB + (wc * 64 + j * 16 + lr) * 32 + lg * 8);
#pragma unroll
        for (int i = 0; i < 4; i++)
#pragma unroll
            for (int j = 0; j < 4; j++)
                acc[i][j] = __builtin_amdgcn_mfma_f32_16x16x32_bf16(a[i], b[j], acc[i][j], 0, 0, 0);
        __syncthreads();
        buf ^= 1;
    }

#pragma unroll
    for (int j = 0; j < 4; j++) {
        int e = n0 + wc * 64 + j * 16 + lr;
        float bv = bias[e];
        int sec = e >> 10;
        int el = e & 1023;
        int h = el >> 6, d = el & 63;
        __hip_bfloat16* dst = (sec == 0) ? Qb : ((sec == 1) ? Kb : Vb);
        // Q carries 1/sqrt(64) * log2(e) so attention can use exp2 directly
        float scale = (sec == 0) ? 0.18033688011112042f : 1.0f;
#pragma unroll
        for (int i = 0; i < 4; i++) {
            int mb = m0 + wr * 64 + i * 16 + lg * 4;
#pragma unroll
            for (int r = 0; r < 4; r++) {
                int tok = mb + r;
                int bb = tok >> 11, l = tok & 2047;
                float v = (acc[i][j][r] + bv) * scale;
                dst[((size_t)(bb * 16 + h) * 2048 + l) * 64 + d] = __float2bfloat16(v);
            }
        }
    }
}

// ---------------- V transpose: [bh][l][64] -> [bh][64][L] ----------------
__global__ __launch_bounds__(256) void transpose_v(const __hip_bfloat16* __restrict__ V,
                                                   __hip_bfloat16* __restrict__ Vt) {
    __shared__ unsigned short tb[64][72];
    int bh = blockIdx.y, l0 = blockIdx.x * 64;
    int tid = threadIdx.x;
    const unsigned short* src = (const unsigned short*)V + ((size_t)bh * 2048 + l0) * 64;
#pragma unroll
    for (int i = 0; i < 2; i++) {
        int idx = i * 256 + tid;
        int row = idx >> 3;
        int c0 = (idx & 7) * 8;
        short8 v = *reinterpret_cast<const short8*>(src + row * 64 + c0);
#pragma unroll
        for (int jj = 0; jj < 8; jj++) tb[c0 + jj][row] = (unsigned short)v[jj];
    }
    __syncthreads();
    unsigned short* dst = (unsigned short*)Vt + (size_t)bh * 64 * 2048 + l0;
#pragma unroll
    for (int i = 0; i < 2; i++) {
        int idx = i * 256 + tid;
        int d = idx >> 3;
        int c8 = (idx & 7) * 8;
        short8 vv = *reinterpret_cast<const short8*>(&tb[d][c8]);
        *reinterpret_cast<short8*>(dst + (size_t)d * 2048 + c8) = vv;
    }
}

// ---------------- causal flash attention ----------------
// 1024 blocks, one 64-row q-tile each, qt DESCENDING in dispatch order so
// long blocks start first and short ones backfill (3 blocks/CU, LDS-capped).
// XCD-pinned: bid&7 = XCD, 4 bh per XCD -> KV+Q working set ~3MB < 4MB L2.
// Swapped QK^T, collapsed LDS addressing, exp2 softmax, defer-max rescale,
// lane-local lsum (cross-lane reduce deferred to epilogue), setprio on MFMA.
__global__ __launch_bounds__(256) void attn(const __hip_bfloat16* __restrict__ Qg,
                                            const __hip_bfloat16* __restrict__ Kg,
                                            const __hip_bfloat16* __restrict__ Vtg,
                                            __hip_bfloat16* __restrict__ ctx) {
    const int bid = blockIdx.x;
    const int xcd = bid & 7, seq = bid >> 3;       // seq in [0,128)
    const int bh = (xcd << 2) | (seq & 3);         // 4 bh per XCD
    const int qt = 31 - (seq >> 2);                // descending q-tiles
    const int tid = threadIdx.x, lane = tid & 63, wq = tid >> 6;
    const int lr = lane & 15, lg = lane >> 4;

    __shared__ __hip_bfloat16 Ks[2][64 * 64];    // [kv][dh], swizzled 16B slots
    __shared__ __hip_bfloat16 Vs[2][64 * 64];    // [d][kv],  swizzled 16B slots
    __shared__ __hip_bfloat16 Ps[4][16 * 72];    // per-wave P [q][kv], padded

    const char* kbase = (const char*)Kg + (size_t)bh * (2048 * 64 * 2);
    const char* vbase = (const char*)Vtg + (size_t)bh * (64 * 2048 * 2);
    const int bb = bh >> 4, h = bh & 15;

    // ---- hoisted stage addressing (invariant: (srow+32)&7 == srow&7) ----
    const int srow = tid >> 3;
    const int ssl = (tid & 7) ^ (srow & 7);
    const char* gk0 = kbase + srow * 128 + ssl * 16;          // += kt*8192
    const char* gv0 = vbase + (size_t)srow * 4096 + ssl * 16; // += kt*128

    // ---- hoisted fragment-read offsets (slot = lg^(lr&7), same for all n) --
    const int koffA = lr * 64 + ((lg ^ (lr & 7)) * 8);        // + n*1024
    const int koffB = lr * 64 + (((4 + lg) ^ (lr & 7)) * 8);
    __hip_bfloat16* pwW = &Ps[wq][0] + lr * 72 + lg * 4;      // + n*16
    const __hip_bfloat16* pwR = &Ps[wq][0] + lr * 72 + lg * 8; // +0, +32

    auto stage = [&](int buf, int kt) {
        char* dK = (char*)&Ks[buf][0] + tid * 16;
        char* dV = (char*)&Vs[buf][0] + tid * 16;
        const char* srcK = gk0 + (size_t)kt * 8192;
        const char* srcV = gv0 + (size_t)kt * 128;
        __builtin_amdgcn_global_load_lds(GAS(srcK), LAS(dK), 16, 0, 0);
        __builtin_amdgcn_global_load_lds(GAS(srcK + 4096), LAS(dK + 4096), 16, 0, 0);
        __builtin_amdgcn_global_load_lds(GAS(srcV), LAS(dV), 16, 0, 0);
        __builtin_amdgcn_global_load_lds(GAS(srcV + 131072), LAS(dV + 4096), 16, 0, 0);
    };

    const f32x4 fz = {0.f, 0.f, 0.f, 0.f};
    const int qb = qt * 64 + wq * 16;

    const __hip_bfloat16* Qrow = Qg + ((size_t)bh * 2048 + qb + lr) * 64 + lg * 8;
    short8 qf0 = *reinterpret_cast<const short8*>(Qrow);
    short8 qf1 = *reinterpret_cast<const short8*>(Qrow + 32);

    f32x4 o[4];
#pragma unroll
    for (int n = 0; n < 4; n++) o[n] = fz;
    float m = -1e30f, lsum = 0.f;   // lsum is lane-local; reduced in epilogue

    const int NT = qt + 1;
    stage(0, 0);
    __syncthreads();
    int buf = 0;
    for (int kt = 0; kt < NT; ++kt) {
        if (kt + 1 < NT) stage(buf ^ 1, kt + 1);
        const __hip_bfloat16* sK = &Ks[buf][0];
        const __hip_bfloat16* sV = &Vs[buf][0];

        // S^T = K Q^T : lane owns q-row lr; kv = n*16 + lg*4 + r
        f32x4 s[4];
#pragma unroll
        for (int n = 0; n < 4; n++) s[n] = fz;
        __builtin_amdgcn_s_setprio(1);
#pragma unroll
        for (int n = 0; n < 4; n++) {
            short8 k0 = *reinterpret_cast<const short8*>(sK + koffA + n * 1024);
            short8 k1 = *reinterpret_cast<const short8*>(sK + koffB + n * 1024);
            s[n] = __builtin_amdgcn_mfma_f32_16x16x32_bf16(k0, qf0, s[n], 0, 0, 0);
            s[n] = __builtin_amdgcn_mfma_f32_16x16x32_bf16(k1, qf1, s[n], 0, 0, 0);
        }
        __builtin_amdgcn_s_setprio(0);

        if (kt == NT - 1) {   // causal mask on the diagonal tile
            int q = qb + lr;
#pragma unroll
            for (int n = 0; n < 4; n++) {
                int kvb = kt * 64 + n * 16 + lg * 4;
#pragma unroll
                for (int r = 0; r < 4; r++)
                    if (kvb + r > q) s[n][r] = -1e30f;
            }
        }

        // row max (lane-local + 2 shuffles)
        float mx = fmaxf(fmaxf(fmaxf(s[0][0], s[0][1]), fmaxf(s[0][2], s[0][3])),
                         fmaxf(fmaxf(fmaxf(s[1][0], s[1][1]), fmaxf(s[1][2], s[1][3])),
                               fmaxf(fmaxf(fmaxf(s[2][0], s[2][1]), fmaxf(s[2][2], s[2][3])),
                                     fmaxf(fmaxf(s[3][0], s[3][1]), fmaxf(s[3][2], s[3][3])))));
        mx = fmaxf(mx, __shfl_xor(mx, 16));
        mx = fmaxf(mx, __shfl_xor(mx, 32));

        // defer-max: only rescale when some row grew by > 8*log2e
        if (!__all(mx - m <= 11.54f)) {
            float mnew = fmaxf(m, mx);
            float corr = __builtin_amdgcn_exp2f(m - mnew);
            m = mnew;
            lsum *= corr;          // corr is row-uniform -> lane-local ok
            float c0 = __shfl(corr, (lane & 48) | (lg * 4 + 0));
            float c1 = __shfl(corr, (lane & 48) | (lg * 4 + 1));
            float c2 = __shfl(corr, (lane & 48) | (lg * 4 + 2));
            float c3 = __shfl(corr, (lane & 48) | (lg * 4 + 3));
#pragma unroll
            for (int n = 0; n < 4; n++) {
                o[n][0] *= c0; o[n][1] *= c1; o[n][2] *= c2; o[n][3] *= c3;
            }
        }

        // P = 2^(S - m); lane-local partial row-sum (no per-iter shuffles)
        float psum = 0.f;
#pragma unroll
        for (int n = 0; n < 4; n++) {
            float p0 = __builtin_amdgcn_exp2f(s[n][0] - m);
            float p1 = __builtin_amdgcn_exp2f(s[n][1] - m);
            float p2 = __builtin_amdgcn_exp2f(s[n][2] - m);
            float p3 = __builtin_amdgcn_exp2f(s[n][3] - m);
            s[n][0] = p0; s[n][1] = p1; s[n][2] = p2; s[n][3] = p3;
            psum += (p0 + p1) + (p2 + p3);
        }
        lsum += psum;

        // P -> per-wave LDS (A-fragment layout)
#pragma unroll
        for (int n = 0; n < 4; n++) {
            short4v pk;
            pk[0] = f2bf_bits(s[n][0]); pk[1] = f2bf_bits(s[n][1]);
            pk[2] = f2bf_bits(s[n][2]); pk[3] = f2bf_bits(s[n][3]);
            *reinterpret_cast<short4v*>(pwW + n * 16) = pk;
        }
        asm volatile("s_waitcnt lgkmcnt(0)" ::: "memory");
        short8 pa0 = *reinterpret_cast<const short8*>(pwR);
        short8 pa1 = *reinterpret_cast<const short8*>(pwR + 32);

        // PV: O[q][d] += P V  (V fragments reuse koffA/koffB)
        __builtin_amdgcn_s_setprio(1);
#pragma unroll
        for (int n = 0; n < 4; n++) {
            short8 vf0 = *reinterpret_cast<const short8*>(sV + koffA + n * 1024);
            short8 vf1 = *reinterpret_cast<const short8*>(sV + koffB + n * 1024);
            o[n] = __builtin_amdgcn_mfma_f32_16x16x32_bf16(pa0, vf0, o[n], 0, 0, 0);
            o[n] = __builtin_amdgcn_mfma_f32_16x16x32_bf16(pa1, vf1, o[n], 0, 0, 0);
        }
        __builtin_amdgcn_s_setprio(0);
        __syncthreads();
        buf ^= 1;
    }

    // epilogue: complete the deferred row-sum, normalize, store
    lsum += __shfl_xor(lsum, 16);
    lsum += __shfl_xor(lsum, 32);
    float l0 = __shfl(lsum, (lane & 48) | (lg * 4 + 0));
    float l1 = __shfl(lsum, (lane & 48) | (lg * 4 + 1));
    float l2 = __shfl(lsum, (lane & 48) | (lg * 4 + 2));
    float l3 = __shfl(lsum, (lane & 48) | (lg * 4 + 3));
    float inv[4] = {1.0f / l0, 1.0f / l1, 1.0f / l2, 1.0f / l3};
#pragma unroll
    for (int r = 0; r < 4; r++) {
        int tok = qb + lg * 4 + r;
        __hip_bfloat16* crow = ctx + ((size_t)(bb * 2048 + tok)) * 1024 + h * 64;
#pragma unroll
        for (int n = 0; n < 4; n++) crow[n * 16 + lr] = __float2bfloat16(o[n][r] * inv[r]);
    }
}

// ---------------- output projection GEMM (128x64 tile) ----------------
// 1D grid 512, XCD-chunked: per XCD 16(bx) x 4(by) -> ~3MB L2 working set.
__global__ __launch_bounds__(256) void gemm_out(const __hip_bfloat16* __restrict__ A,
                                                const __hip_bfloat16* __restrict__ B,
                                                const float* __restrict__ bias,
                                                float* __restrict__ out) {
    constexpr int K = 1024;
    __shared__ __hip_bfloat16 smem[2][128 * 32 + 64 * 32];
    const int tid = threadIdx.x;
    const int lane = tid & 63, wid = tid >> 6;
    const int wr = wid >> 1, wc = wid & 1;
    const int lr = lane & 15, lg = lane >> 4;

    const int bid = blockIdx.x;
    const int xcd = bid & 7, w = bid >> 3;     // w in [0,64)
    const int bx = w & 15;                     // [0,16)
    const int by = (xcd << 2) | (w >> 4);      // [0,32)
    const int m0 = by * 128;
    const int n0 = bx * 64;

    const f32x4 fz = {0.f, 0.f, 0.f, 0.f};
    f32x4 acc[4][2];
#pragma unroll
    for (int i = 0; i < 4; i++)
#pragma unroll
        for (int j = 0; j < 2; j++) acc[i][j] = fz;

    const char* Abase = (const char*)A + (size_t)m0 * K * 2;
    const char* Bbase = (const char*)B + (size_t)n0 * K * 2;

    auto stage = [&](int buf, int kt) {
        const int kb = kt * 64;
        char* sA = (char*)&smem[buf][0];
        char* sB = (char*)&smem[buf][128 * 32];
#pragma unroll
        for (int i = 0; i < 2; i++) {
            int o = i * 4096 + tid * 16;
            int row = o >> 6, cb = o & 63;
            __builtin_amdgcn_global_load_lds(GAS(Abase + (size_t)row * 2048 + kb + cb),
                                             LAS(sA + o), 16, 0, 0);
        }
        {
            int o = tid * 16;
            int row = o >> 6, cb = o & 63;
            __builtin_amdgcn_global_load_lds(GAS(Bbase + (size_t)row * 2048 + kb + cb),
                                             LAS(sB + o), 16, 0, 0);
        }
    };

    stage(0, 0);
    __syncthreads();
    int buf = 0;
    constexpr int NT = K / 32;
    for (int kt = 0; kt < NT; ++kt) {
        if (kt + 1 < NT) stage(buf ^ 1, kt + 1);
        const __hip_bfloat16* sA = &smem[buf][0];
        const __hip_bfloat16* sB = &smem[buf][128 * 32];
        short8 a[4], b[2];
#pragma unroll
        for (int i = 0; i < 4; i++)
            a[i] = *reinterpret_cast<const short8*>(sA + (wr * 64 + i * 16 + lr) * 32 + lg * 8);
#pragma unroll
        for (int j = 0; j < 2; j++)
            b[j] = *reinterpret_cast<const short8*>(sB + (wc * 32 + j * 16 + lr) * 32 + lg * 8);
#pragma unroll
        for (int i = 0; i < 4; i++)
#pragma unroll
            for (int j = 0; j < 2; j++)
                acc[i][j] = __builtin_amdgcn_mfma_f32_16x16x32_bf16(a[i], b[j], acc[i][j], 0, 0, 0);
        __syncthreads();
        buf ^= 1;
    }

#pragma unroll
    for (int j = 0; j < 2; j++) {
        int e = n0 + wc * 32 + j * 16 + lr;
        float bv = bias[e];
#pragma unroll
        for (int i = 0; i < 4; i++) {
            int mb = m0 + wr * 64 + i * 16 + lg * 4;
#pragma unroll
            for (int r = 0; r < 4; r++) {
                out[(size_t)(mb + r) * 1024 + e] = acc[i][j][r] + bv;
            }
        }
    }
}

extern "C" void kernel_launch(void* const* d_in, const int* in_sizes, int n_in,
                              void* d_out, int out_size, void* d_ws, size_t ws_size,
                              hipStream_t stream) {
    const float* x = (const float*)d_in[0];
    const float* w_in = (const float*)d_in[1];
    const float* b_in = (const float*)d_in[2];
    const float* w_out = (const float*)d_in[3];
    const float* b_out = (const float*)d_in[4];
    float* out = (float*)d_out;

    char* ws = (char*)d_ws;
    __hip_bfloat16* xbf  = (__hip_bfloat16*)(ws);
    __hip_bfloat16* wbf  = (__hip_bfloat16*)(ws + (8ull << 20));
    __hip_bfloat16* owbf = (__hip_bfloat16*)(ws + (14ull << 20));
    __hip_bfloat16* Qb   = (__hip_bfloat16*)(ws + (16ull << 20));
    __hip_bfloat16* Kb   = (__hip_bfloat16*)(ws + (24ull << 20));
    __hip_bfloat16* Vb   = (__hip_bfloat16*)(ws + (32ull << 20));
    __hip_bfloat16* Vt   = (__hip_bfloat16*)(ws + (40ull << 20));
    __hip_bfloat16* ctxb = (__hip_bfloat16*)(ws + (48ull << 20));

    cvt_all<<<4096, 256, 0, stream>>>(x, w_in, w_out, (short*)xbf, (short*)wbf, (short*)owbf);
    gemm_qkv<<<768, 256, 0, stream>>>(xbf, wbf, b_in, Qb, Kb, Vb);
    transpose_v<<<dim3(32, 32), 256, 0, stream>>>(Vb, Vt);
    attn<<<1024, 256, 0, stream>>>(Qb, Kb, Vt, ctxb);
    gemm_out<<<512, 256, 0, stream>>>(ctxb, owbf, b_out, out);
}